// Round 12
// baseline (3193.869 us; speedup 1.0000x reference)
//
#include <hip/hip_runtime.h>
#include <hip/hip_bf16.h>
#include <math.h>

typedef unsigned short u16t;
using f32x4 = __attribute__((ext_vector_type(4))) float;
using s16x8 = __attribute__((ext_vector_type(8))) short;
using us8   = __attribute__((ext_vector_type(8))) unsigned short;

#define GB_RELU 1
#define GB_WF32 4
#define GB_WB16 8

__device__ __forceinline__ u16t f2b(float f) {
    unsigned u = __float_as_uint(f);
    unsigned r = (u + 0x7FFFu + ((u >> 16) & 1u)) >> 16;
    return (u16t)r;
}
__device__ __forceinline__ float b2f(u16t s) {
    return __uint_as_float(((unsigned)s) << 16);
}
__device__ __forceinline__ void gload16(const void* gsrc, void* ldst) {
    __builtin_amdgcn_global_load_lds(
        (const __attribute__((address_space(1))) void*)gsrc,
        (__attribute__((address_space(3))) void*)ldst, 16, 0, 0);
}

// ---------------------------------------------------------------------------
// bf16 MFMA GEMM, single-buffered m97-style schedule (STAGE; vmcnt0; barrier;
// compute; barrier), 34.8 KB LDS -> 3 blocks/CU, swizzled LDS, XCD-chunked
// block swizzle, LDS-staged coalesced bf16 epilogue.
// C[M,N] = A[M,K](bf16) @ W[N,K]^T(bf16) + bias; relu opt.
// 128x128 tile, BK=64, 512 thr (8 waves, 2Mx4N), acc[4][2]/wave.
// ---------------------------------------------------------------------------
__global__ __launch_bounds__(512, 6)
void gemm_bf16(const u16t* __restrict__ A, int lda,
               const u16t* __restrict__ W, int ldw,
               const float* __restrict__ bias,
               float* __restrict__ C, int ldc,
               u16t* __restrict__ Cb, int ldcb,
               int M, int N, int K, int flags)
{
    __shared__ u16t SM[17408];          // 34.8 KiB: As[8192] | Ws[8192] (+epilogue)
    u16t* As = SM;
    u16t* Ws = SM + 8192;
    const int tid = threadIdx.x;
    const int lane = tid & 63, w = tid >> 6;
    const int wr = w >> 2, wc = w & 3;       // 2M x 4N wave grid
    const int l15 = lane & 15, l4 = lane >> 4;

    // XCD-chunked bijective swizzle (only when nwg % 8 == 0)
    unsigned nwg = gridDim.x * gridDim.y;
    unsigned bid = blockIdx.y * gridDim.x + blockIdx.x;
    if ((nwg & 7u) == 0u) bid = (bid & 7u) * (nwg >> 3) + (bid >> 3);
    const int m0 = (int)(bid / gridDim.x) * 128;
    const int n0 = (int)(bid % gridDim.x) * 128;

    int arow[2], wrow[2], koff[2], se0[2];
#pragma unroll
    for (int it = 0; it < 2; ++it) {
        const int e = it * 512 + tid;          // 16B unit 0..1023
        se0[it] = it * 512 + (tid & 448);      // wave-uniform base
        const int kb = e >> 7, r = e & 127;
        const int rg = r ^ (kb & 3);
        int gm = m0 + rg; if (gm > M - 1) gm = M - 1;
        arow[it] = gm;
        wrow[it] = n0 + rg;
        koff[it] = kb * 8;
    }

    f32x4 acc[4][2];
#pragma unroll
    for (int i = 0; i < 4; ++i)
#pragma unroll
        for (int j = 0; j < 2; ++j) acc[i][j] = (f32x4){0.f, 0.f, 0.f, 0.f};

    auto STAGE = [&](int k0) {
#pragma unroll
        for (int it = 0; it < 2; ++it)
            gload16(A + (size_t)arow[it] * lda + k0 + koff[it],
                    &As[(size_t)se0[it] * 8]);
#pragma unroll
        for (int it = 0; it < 2; ++it)
            gload16(W + (size_t)wrow[it] * ldw + k0 + koff[it],
                    &Ws[(size_t)se0[it] * 8]);
    };

    const int nk = K >> 6;
    for (int ks = 0; ks < nk; ++ks) {
        STAGE(ks << 6);
        asm volatile("s_waitcnt vmcnt(0)" ::: "memory");
        __builtin_amdgcn_s_barrier();
#pragma unroll
        for (int kk = 0; kk < 2; ++kk) {
            const int kb = kk * 4 + l4;
            const int ls = l15 ^ l4;     // swizzled row-within-16 on read
            s16x8 a[4], b[2];
#pragma unroll
            for (int mi = 0; mi < 4; ++mi)
                a[mi] = *(const s16x8*)&As[(size_t)((kb * 128 + wr * 64 + mi * 16 + ls) * 8)];
#pragma unroll
            for (int ni = 0; ni < 2; ++ni)
                b[ni] = *(const s16x8*)&Ws[(size_t)((kb * 128 + wc * 32 + ni * 16 + ls) * 8)];
#pragma unroll
            for (int mi = 0; mi < 4; ++mi)
#pragma unroll
                for (int ni = 0; ni < 2; ++ni)
                    acc[mi][ni] = __builtin_amdgcn_mfma_f32_16x16x32_bf16(
                        a[mi], b[ni], acc[mi][ni], 0, 0, 0);
        }
        if (ks + 1 < nk) __builtin_amdgcn_s_barrier();
    }

    // epilogue
    if (flags & GB_WB16) __syncthreads();
#pragma unroll
    for (int mi = 0; mi < 4; ++mi) {
#pragma unroll
        for (int r = 0; r < 4; ++r) {
            const int rowl = wr * 64 + mi * 16 + l4 * 4 + r;
            const int row = m0 + rowl;
            const bool rok = row < M;
#pragma unroll
            for (int ni = 0; ni < 2; ++ni) {
                const int coll = wc * 32 + ni * 16 + l15;
                float v = acc[mi][ni][r];
                if (bias) v += bias[n0 + coll];
                if (flags & GB_RELU) v = fmaxf(v, 0.f);
                if ((flags & GB_WF32) && rok) C[(size_t)row * ldc + n0 + coll] = v;
                if (flags & GB_WB16) SM[rowl * 136 + coll] = f2b(v);
            }
        }
    }
    if (flags & GB_WB16) {
        __syncthreads();
#pragma unroll
        for (int rr = 0; rr < 4; ++rr) {
            const int rowl = rr * 32 + (tid >> 4);
            const int c0 = (tid & 15) * 8;
            if (m0 + rowl < M)
                *(us8*)(Cb + (size_t)(m0 + rowl) * ldcb + n0 + c0) =
                    *(const us8*)&SM[rowl * 136 + c0];
        }
    }
}

// ---------------------------------------------------------------------------
// FSMN sliding-window mean, vectorized (ushort4 = 4 d per thread).
// In-place on HM[M,1024]: reads cols 0-511 (h), writes cols 512-1023.
// grid 128 blocks, 256 thr; each 128-thread group = one (b, 64-row chunk).
// ---------------------------------------------------------------------------
__global__ __launch_bounds__(256)
void fsmn_means_b(u16t* __restrict__ HM, int stride)
{
    const int g = blockIdx.x * 2 + (threadIdx.x >> 7);   // 0..255
    const int t = threadIdx.x & 127;
    const int b = g >> 5, chunk = g & 31;                // 8 b x 32 chunks
    const int c0 = chunk * 64;
    const int d0 = t * 4;
    const u16t* Hp = HM + (size_t)b * 2048 * 1024 + d0;
    u16t* Mp = HM + (size_t)b * 2048 * 1024 + 512 + d0;
    float s0 = 0.f, s1 = 0.f, s2 = 0.f, s3 = 0.f;
    int j0 = c0 - stride; if (j0 < 0) j0 = 0;
    for (int j = j0; j < c0; ++j) {
        const ushort4 hv = *(const ushort4*)(Hp + (size_t)j * 1024);
        s0 += b2f(hv.x); s1 += b2f(hv.y); s2 += b2f(hv.z); s3 += b2f(hv.w);
    }
    for (int i = c0; i < c0 + 64; ++i) {
        const ushort4 hv = *(const ushort4*)(Hp + (size_t)i * 1024);
        s0 += b2f(hv.x); s1 += b2f(hv.y); s2 += b2f(hv.z); s3 += b2f(hv.w);
        const int st = i - stride;
        const float cnt = (float)(i + 1 - (st > 0 ? st : 0));
        ushort4 ov;
        ov.x = f2b(s0 / cnt); ov.y = f2b(s1 / cnt);
        ov.z = f2b(s2 / cnt); ov.w = f2b(s3 / cnt);
        *(ushort4*)(Mp + (size_t)i * 1024) = ov;
        if (st >= 0) {
            const ushort4 hs = *(const ushort4*)(Hp + (size_t)st * 1024);
            s0 -= b2f(hs.x); s1 -= b2f(hs.y); s2 -= b2f(hs.z); s3 -= b2f(hs.w);
        }
    }
}

// ---------------------------------------------------------------------------
// ci[b,l,s] = dot(HM[b,l,0:512], SF[b,s,:]) — one thread per row, all 4 s.
// grid 64 blocks x 256 thr. HM read once.
// ---------------------------------------------------------------------------
__global__ __launch_bounds__(256)
void ci_kernel(const u16t* __restrict__ HM, const float* __restrict__ SF,
               float* __restrict__ CI)
{
    const int bl = blockIdx.x * 256 + threadIdx.x;   // 0..16383
    const int b = bl >> 11;
    const us8* h8 = (const us8*)(HM + (size_t)bl * 1024);
    const float4* f4 = (const float4*)(SF + (size_t)b * 4 * 512);
    float a0 = 0.f, a1 = 0.f, a2 = 0.f, a3 = 0.f;
    for (int k = 0; k < 64; ++k) {
        const us8 hv = h8[k];
        float hf[8];
#pragma unroll
        for (int j = 0; j < 8; ++j) hf[j] = b2f(hv[j]);
#pragma unroll
        for (int s = 0; s < 4; ++s) {
            const float4 x = f4[s * 128 + k * 2];
            const float4 y = f4[s * 128 + k * 2 + 1];
            const float d = hf[0] * x.x + hf[1] * x.y + hf[2] * x.z + hf[3] * x.w
                          + hf[4] * y.x + hf[5] * y.y + hf[6] * y.z + hf[7] * y.w;
            if (s == 0) a0 += d; else if (s == 1) a1 += d;
            else if (s == 2) a2 += d; else a3 += d;
        }
    }
    float4 outv = make_float4(a0, a1, a2, a3);
    *(float4*)(CI + (size_t)bl * 4) = outv;
}

// ---------------------------------------------------------------------------
// Y(ld512,f32) = LN(X + Rb) * w + b ; Rb bf16 ld512; Yb(ld1024,bf16).
// ---------------------------------------------------------------------------
__global__ __launch_bounds__(256)
void ln_add_f32(const float* __restrict__ X, const u16t* __restrict__ Rb,
                const float* __restrict__ w, const float* __restrict__ b,
                float* __restrict__ Y, u16t* __restrict__ Yb)
{
    const int lane = threadIdx.x & 63, wid = threadIdx.x >> 6;
    const size_t row = (size_t)blockIdx.x * 4 + wid;
    const float* x = X + row * 512;
    const u16t* r = Rb + row * 512;
    const int c0 = lane * 8;
    float v[8];
    {
        const float4 a0 = *(const float4*)(x + c0);
        const float4 a1 = *(const float4*)(x + c0 + 4);
        const us8 r8 = *(const us8*)(r + c0);
        v[0] = a0.x + b2f(r8[0]); v[1] = a0.y + b2f(r8[1]);
        v[2] = a0.z + b2f(r8[2]); v[3] = a0.w + b2f(r8[3]);
        v[4] = a1.x + b2f(r8[4]); v[5] = a1.y + b2f(r8[5]);
        v[6] = a1.z + b2f(r8[6]); v[7] = a1.w + b2f(r8[7]);
    }
    float s = 0.f;
#pragma unroll
    for (int j = 0; j < 8; ++j) s += v[j];
#pragma unroll
    for (int off = 1; off < 64; off <<= 1) s += __shfl_xor(s, off);
    const float mean = s * (1.f / 512.f);
    float q = 0.f;
#pragma unroll
    for (int j = 0; j < 8; ++j) { const float dd = v[j] - mean; q += dd * dd; }
#pragma unroll
    for (int off = 1; off < 64; off <<= 1) q += __shfl_xor(q, off);
    const float rstd = rsqrtf(q * (1.f / 512.f) + 1e-5f);
    float* y = Y + row * 512;
    u16t* yb = Yb + row * 1024;
#pragma unroll
    for (int j = 0; j < 8; ++j) {
        const float o = (v[j] - mean) * rstd * w[c0 + j] + b[c0 + j];
        y[c0 + j] = o;
        yb[c0 + j] = f2b(o);
    }
}

// ---------------------------------------------------------------------------
// V transpose: Vt[b,h,d,l] (bf16) from QKVb[b,l,1024+h*128+d] (bf16).
// grid (L/64, B*H), block 256.
// ---------------------------------------------------------------------------
__global__ __launch_bounds__(256)
void vtprep(const u16t* __restrict__ QKVb, u16t* __restrict__ Vt)
{
    __shared__ u16t T[128 * 72];
    const int tid = threadIdx.x;
    const int l0 = blockIdx.x * 64;
    const int bh = blockIdx.y, b = bh >> 2, h = bh & 3;
#pragma unroll
    for (int it = 0; it < 4; ++it) {
        const int e = it * 256 + tid;
        const int l = e >> 4, dc = e & 15;
        const us8 v = *(const us8*)(QKVb + ((size_t)(b * 2048 + l0 + l)) * 1536
                                   + 1024 + h * 128 + dc * 8);
#pragma unroll
        for (int j = 0; j < 8; ++j) T[(dc * 8 + j) * 72 + l] = v[j];
    }
    __syncthreads();
#pragma unroll
    for (int it = 0; it < 4; ++it) {
        const int e = it * 256 + tid;
        const int d = e >> 3, lc = e & 7;
        const us8 ov = *(const us8*)&T[d * 72 + lc * 8];
        *(us8*)(Vt + ((size_t)bh * 128 + d) * 2048 + l0 + lc * 8) = ov;
    }
}

// ---------------------------------------------------------------------------
// MFMA flash attention, 2-phase pipelined (counted vmcnt), defer-max THR=8,
// grid (16, 32) = 512 blocks, 512 thr. XCD-grouped (b,h).  [round-7 proven]
// ---------------------------------------------------------------------------
__global__ __launch_bounds__(512)
void attn_bf16(const u16t* __restrict__ QKVb, const u16t* __restrict__ Vt,
               u16t* __restrict__ AOb)
{
    __shared__ u16t Kt[2][8192];
    __shared__ u16t Vtl[2][8192];
    __shared__ u16t Pl[8192];
    const int tid = threadIdx.x, lane = tid & 63, w = tid >> 6;
    const int l15 = lane & 15, l4 = lane >> 4;
    const unsigned bid = blockIdx.y * gridDim.x + blockIdx.x;  // 0..511
    const int xcd = bid & 7, idx = bid >> 3;
    const int bh = xcd * 4 + (idx & 3);
    const int q0 = (idx >> 2) * 128;
    const int b = bh >> 2, h = bh & 3;
    const float SCALE = 0.08838834764831845f;   // 1/sqrt(128)

    int krow[2], kdoff[2], vd[2], vkoff[2], se0[2];
#pragma unroll
    for (int it = 0; it < 2; ++it) {
        const int e = it * 512 + tid;
        se0[it] = it * 512 + (tid & 448);
        const int dblk = e >> 6, key = e & 63;
        krow[it] = key ^ (dblk & 3);
        kdoff[it] = dblk * 8;
        const int kb = e >> 7, d = e & 127;
        vd[it] = d ^ (kb & 3);
        vkoff[it] = kb * 8;
    }
    auto STAGE = [&](int buf, int k0) {
#pragma unroll
        for (int it = 0; it < 2; ++it)
            gload16(QKVb + ((size_t)(b * 2048 + k0 + krow[it])) * 1536 + 512 + h * 128 + kdoff[it],
                    &Kt[buf][(size_t)se0[it] * 8]);
#pragma unroll
        for (int it = 0; it < 2; ++it)
            gload16(Vt + ((size_t)bh * 128 + vd[it]) * 2048 + k0 + vkoff[it],
                    &Vtl[buf][(size_t)se0[it] * 8]);
    };

    s16x8 qf[4];
    {
        const u16t* qp = QKVb + ((size_t)(b * 2048 + q0 + w * 16 + l15)) * 1536
                         + h * 128 + l4 * 8;
#pragma unroll
        for (int ks = 0; ks < 4; ++ks) qf[ks] = *(const s16x8*)(qp + ks * 32);
    }
    asm volatile("s_waitcnt vmcnt(0)" ::: "memory");

    f32x4 o[8];
#pragma unroll
    for (int i = 0; i < 8; ++i) o[i] = (f32x4){0.f, 0.f, 0.f, 0.f};
    f32x4 m_run, lsum;
#pragma unroll
    for (int r = 0; r < 4; ++r) { m_run[r] = -1e30f; lsum[r] = 0.f; }

    const int ls = l15 ^ l4;
    STAGE(0, 0);
    for (int kt = 0; kt < 32; ++kt) {
        const int cur = kt & 1;
        if (kt + 1 < 32) {
            STAGE(cur ^ 1, (kt + 1) * 64);
            asm volatile("s_waitcnt vmcnt(4)" ::: "memory");
        } else {
            asm volatile("s_waitcnt vmcnt(0)" ::: "memory");
        }
        __builtin_amdgcn_s_barrier();

        f32x4 s[4];
#pragma unroll
        for (int ni = 0; ni < 4; ++ni) s[ni] = (f32x4){0.f, 0.f, 0.f, 0.f};
#pragma unroll
        for (int ks = 0; ks < 4; ++ks) {
#pragma unroll
            for (int ni = 0; ni < 4; ++ni) {
                const s16x8 kf = *(const s16x8*)&Kt[cur][(size_t)((ks * 4 + l4) * 64 + ni * 16 + ls) * 8];
                s[ni] = __builtin_amdgcn_mfma_f32_16x16x32_bf16(qf[ks], kf, s[ni], 0, 0, 0);
            }
        }
        f32x4 mx;
#pragma unroll
        for (int r = 0; r < 4; ++r)
            mx[r] = fmaxf(fmaxf(s[0][r], s[1][r]), fmaxf(s[2][r], s[3][r])) * SCALE;
#pragma unroll
        for (int off = 1; off < 16; off <<= 1)
#pragma unroll
            for (int r = 0; r < 4; ++r) mx[r] = fmaxf(mx[r], __shfl_xor(mx[r], off));
        bool small = true;
#pragma unroll
        for (int r = 0; r < 4; ++r) small = small && (mx[r] <= m_run[r] + 8.f);
        if (!__all(small)) {
            f32x4 corr;
#pragma unroll
            for (int r = 0; r < 4; ++r) {
                const float nm = fmaxf(m_run[r], mx[r]);
                corr[r] = __expf(m_run[r] - nm);
                m_run[r] = nm;
                lsum[r] *= corr[r];
            }
#pragma unroll
            for (int ni = 0; ni < 8; ++ni)
#pragma unroll
                for (int r = 0; r < 4; ++r) o[ni][r] *= corr[r];
        }
        float p[4][4];
#pragma unroll
        for (int ni = 0; ni < 4; ++ni)
#pragma unroll
            for (int r = 0; r < 4; ++r) {
                p[ni][r] = __expf(s[ni][r] * SCALE - m_run[r]);
                lsum[r] += p[ni][r];
            }
#pragma unroll
        for (int ni = 0; ni < 4; ++ni) {
            const int key = ni * 16 + l15;
            const int kb = key >> 3, kj = key & 7;
#pragma unroll
            for (int r = 0; r < 4; ++r)
                Pl[(size_t)((w * 8 + kb) * 16 + l4 * 4 + r) * 8 + kj] = f2b(p[ni][r]);
        }
#pragma unroll
        for (int kk = 0; kk < 2; ++kk) {
            const s16x8 pa = *(const s16x8*)&Pl[(size_t)((w * 8 + kk * 4 + l4) * 16 + l15) * 8];
#pragma unroll
            for (int ni = 0; ni < 8; ++ni) {
                const s16x8 vf = *(const s16x8*)&Vtl[cur][(size_t)((kk * 4 + l4) * 128 + ni * 16 + ls) * 8];
                o[ni] = __builtin_amdgcn_mfma_f32_16x16x32_bf16(pa, vf, o[ni], 0, 0, 0);
            }
        }
        __builtin_amdgcn_s_barrier();
    }
#pragma unroll
    for (int off = 1; off < 16; off <<= 1)
#pragma unroll
        for (int r = 0; r < 4; ++r) lsum[r] += __shfl_xor(lsum[r], off);
    f32x4 inv;
#pragma unroll
    for (int r = 0; r < 4; ++r) inv[r] = 1.f / lsum[r];
#pragma unroll
    for (int ni = 0; ni < 8; ++ni)
#pragma unroll
        for (int r = 0; r < 4; ++r)
            AOb[((size_t)(b * 2048 + q0 + w * 16 + l4 * 4 + r)) * 512
                + h * 128 + ni * 16 + l15] = f2b(o[ni][r] * inv[r]);
}

// ---------------------------------------------------------------------------
// concat -> padded bf16 [M,576], vectorized (4-col groups; 576 = 144*4).
// group 0 = ci[0..3]; groups 1..128 = HM h-cols; groups 129..143 = zero.
// ---------------------------------------------------------------------------
__global__ __launch_bounds__(256)
void concat_b(const float* __restrict__ CI, const u16t* __restrict__ HM,
              u16t* __restrict__ OUTC)
{
    const size_t total = (size_t)16384 * 144;
    const size_t i = (size_t)blockIdx.x * 256 + threadIdx.x;
    if (i >= total) return;
    const int gcol = (int)(i % 144);
    const size_t row = i / 144;
    ushort4 v;
    if (gcol == 0) {
        const float4 c = *(const float4*)(CI + row * 4);
        v.x = f2b(c.x); v.y = f2b(c.y); v.z = f2b(c.z); v.w = f2b(c.w);
    } else if (gcol < 129) {
        v = *(const ushort4*)(HM + row * 1024 + (size_t)(gcol - 1) * 4);
    } else {
        v.x = 0; v.y = 0; v.z = 0; v.w = 0;
    }
    *(ushort4*)(OUTC + row * 576 + (size_t)gcol * 4) = v;
}

// ---------------------------------------------------------------------------
// converters
// ---------------------------------------------------------------------------
struct CvtJob { const float* s; u16t* d; unsigned n8; unsigned blk0; };
struct CvtJobs { CvtJob j[8]; };

__global__ __launch_bounds__(256)
void cvt_batch(CvtJobs jobs)
{
    int lo = 0;
#pragma unroll
    for (int i = 1; i < 8; ++i) if (blockIdx.x >= jobs.j[i].blk0) lo = i;
    const float* src = jobs.j[lo].s;
    u16t* dst = jobs.j[lo].d;
    const size_t i = (size_t)(blockIdx.x - jobs.j[lo].blk0) * 256 + threadIdx.x;
    if (i >= jobs.j[lo].n8) return;
    const float4 a = ((const float4*)src)[i * 2];
    const float4 b = ((const float4*)src)[i * 2 + 1];
    us8 o;
    o[0] = f2b(a.x); o[1] = f2b(a.y); o[2] = f2b(a.z); o[3] = f2b(a.w);
    o[4] = f2b(b.x); o[5] = f2b(b.y); o[6] = f2b(b.z); o[7] = f2b(b.w);
    ((us8*)dst)[i] = o;
}

__global__ __launch_bounds__(256)
void cvt_pad(const float* __restrict__ src, u16t* __restrict__ dst,
             int rows, int sc, int dc)
{
    const size_t i = (size_t)blockIdx.x * 256 + threadIdx.x;
    const size_t total = (size_t)rows * dc;
    if (i >= total) return;
    const int c = (int)(i % dc);
    const size_t r = i / dc;
    dst[i] = (c < sc) ? f2b(src[r * sc + c]) : (u16t)0;
}

// fuse [layers,512,512] lw,mw -> [layers,512,1024] ([lw_row | mw_row])
__global__ __launch_bounds__(256)
void cvt_fuse(const float* __restrict__ lsrc, const float* __restrict__ msrc,
              u16t* __restrict__ dst, int n)
{
    const int idx = blockIdx.x * 256 + threadIdx.x;
    if (idx >= n) return;
    const int k = idx & 511;
    const int nn = (idx >> 9) & 511;
    const int i = idx >> 18;
    const size_t base = (size_t)i * 524288 + (size_t)nn * 1024 + k;
    dst[base] = f2b(lsrc[idx]);
    dst[base + 512] = f2b(msrc[idx]);
}

__global__ __launch_bounds__(256)
void bias_fuse(const float* __restrict__ a, const float* __restrict__ b,
               float* __restrict__ dst, int n)
{
    const int i = blockIdx.x * 256 + threadIdx.x;
    if (i < n) dst[i] = a[i] + b[i];
}

// ---------------------------------------------------------------------------
// final tiny GEMM: out[M,16] = T1[M,512] @ W2[16,512]^T + b2   (fp32)
// ---------------------------------------------------------------------------
__global__ __launch_bounds__(256)
void cls2_kernel(const float* __restrict__ T1, const float* __restrict__ W2,
                 const float* __restrict__ b2, float* __restrict__ out)
{
    const int t = threadIdx.x;
    const int r = blockIdx.x * 16 + (t >> 4), c = t & 15;
    const float4* a = (const float4*)(T1 + (size_t)r * 512);
    const float4* wv = (const float4*)(W2 + (size_t)c * 512);
    float acc = 0.f;
    for (int k = 0; k < 128; ++k) {
        const float4 x = a[k], y = wv[k];
        acc += x.x * y.x + x.y * y.y + x.z * y.z + x.w * y.w;
    }
    out[(size_t)r * 16 + c] = acc + b2[c];
}

// ---------------------------------------------------------------------------
extern "C" void kernel_launch(void* const* d_in, const int* in_sizes, int n_in,
                              void* d_out, int out_size, void* d_ws, size_t ws_size,
                              hipStream_t stream)
{
    (void)in_sizes; (void)n_in; (void)out_size; (void)ws_size;
    const int M = 16384;   // B*L

    const float* x        = (const float*)d_in[0];
    const float* spk_emb  = (const float*)d_in[1];
    const float* enc0_w   = (const float*)d_in[2];
    const float* enc0_b   = (const float*)d_in[3];
    const float* enc_lw   = (const float*)d_in[4];
    const float* enc_lb   = (const float*)d_in[5];
    const float* enc_mw   = (const float*)d_in[6];
    const float* enc_mb   = (const float*)d_in[7];
    const float* spk_w1   = (const float*)d_in[8];
    const float* spk_b1   = (const float*)d_in[9];
    const float* spk_w2   = (const float*)d_in[10];
    const float* spk_b2   = (const float*)d_in[11];
    const float* spk_w3   = (const float*)d_in[12];
    const float* spk_b3   = (const float*)d_in[13];
    const float* tr_in_w  = (const float*)d_in[14];
    const float* tr_in_b  = (const float*)d_in[15];
    const float* tr_out_w = (const float*)d_in[16];
    const float* tr_out_b = (const float*)d_in[17];
    const float* tr_ln1_w = (const float*)d_in[18];
    const float* tr_ln1_b = (const float*)d_in[19];
    const float* tr_ff1_w = (const float*)d_in[20];
    const float* tr_ff1_b = (const float*)d_in[21];
    const float* tr_ff2_w = (const float*)d_in[22];
    const float* tr_ff2_b = (const float*)d_in[23];
    const float* tr_ln2_w = (const float*)d_in[24];
    const float* tr_ln2_b = (const float*)d_in[25];
    const float* adpt_w   = (const float*)d_in[26];
    const float* adpt_b   = (const float*)d_in[27];
    const float* post_lw  = (const float*)d_in[28];
    const float* post_lb  = (const float*)d_in[29];
    const float* post_mw  = (const float*)d_in[30];
    const float* post_mb  = (const float*)d_in[31];
    const float* cls_w1   = (const float*)d_in[32];
    const float* cls_b1   = (const float*)d_in[33];
    const float* cls_w2   = (const float*)d_in[34];
    const float* cls_b2   = (const float*)d_in[35];

    // ---- workspace layout ----
    char* wsp = (char*)d_ws;
    size_t off = 0;
    auto alloc = [&](size_t bytes) -> void* {
        void* p = wsp + off; off += (bytes + 255) & ~(size_t)255; return p;
    };
    float* H    = (float*)alloc((size_t)M * 512 * 4);      // fp32 residual stream
    float* T1   = (float*)alloc((size_t)M * 512 * 4);      // fp32 temp (cls1) / T1b
    u16t*  HM0  = (u16t*) alloc((size_t)M * 1024 * 2);     // [h | means] ping
    u16t*  AOb  = (u16t*) alloc((size_t)M * 512 * 2);      // attn out
    u16t*  BIG  = (u16t*) alloc((size_t)M * 2048 * 2);     // HM1 | xb | QKV+Vt | F | Xcat
    float* CI   = (float*)alloc((size_t)M * 4 * 4);
    float* S3   = (float*)alloc(32 * 512 * 4);
    u16t* enc0_wb   = (u16t*)alloc(512 * 128 * 2);
    u16t* encFW     = (u16t*)alloc((size_t)8 * 512 * 1024 * 2);
    float* encFB    = (float*)alloc(8 * 512 * 4);
    u16t* spk_embb  = (u16t*)alloc(32 * 192 * 2);
    u16t* spk_w1b   = (u16t*)alloc(512 * 192 * 2);
    u16t* spk_w2b   = (u16t*)alloc(512 * 512 * 2);
    u16t* spk_w3b   = (u16t*)alloc(512 * 512 * 2);
    u16t* tr_in_wb  = (u16t*)alloc((size_t)4 * 1536 * 512 * 2);
    u16t* tr_out_wb = (u16t*)alloc((size_t)4 * 512 * 512 * 2);
    u16t* tr_ff1_wb = (u16t*)alloc((size_t)4 * 2048 * 512 * 2);
    u16t* tr_ff2_wb = (u16t*)alloc((size_t)4 * 2048 * 512 * 2);
    u16t* adpt_wb   = (u16t*)alloc(512 * 576 * 2);
    u16t* postFW    = (u16t*)alloc((size_t)6 * 512 * 1024 * 2);
    float* postFB   = (float*)alloc(6 * 512 * 4);
    u16t* cls_w1b   = (u16t*)alloc(512 * 512 * 2);
    u16t* S1b       = (u16t*)alloc(32 * 512 * 2);
    u16t* S2b       = (u16t*)alloc(32 * 512 * 2);

    u16t* HM1   = BIG;                       // [M,1024] during FSMN phases
    u16t* xb    = BIG;                       // [M,128] before enc0 only
    u16t* QKVb  = BIG;                       // [M,1536] during transformer
    u16t* Vt    = BIG + (size_t)M * 1536;    // [B*H,128,2048]
    u16t* Fb    = BIG;                       // [M,2048] FFN hidden
    u16t* Xcatb = BIG;                       // [M,576] concat
    u16t* T1b   = (u16t*)T1;                 // bf16 LN-residual (aliases T1)
    u16t* HMs[2] = {HM0, HM1};

    auto cpad = [&](const float* s, u16t* d, int rows, int sc, int dc) {
        const size_t tot = (size_t)rows * dc;
        cvt_pad<<<dim3((unsigned)((tot + 255) / 256)), dim3(256), 0, stream>>>(s, d, rows, sc, dc);
    };
    // 13 params: A,lda, W,ldw, bias, C,ldc, Cb,ldcb, m,n,k, flags
    auto gemm = [&](const u16t* A, int lda, const u16t* W, int ldw,
                    const float* bias, float* C, int ldc, u16t* Cb, int ldcb,
                    int m, int n, int k, int flags) {
        dim3 g(n / 128, (m + 127) / 128);
        gemm_bf16<<<g, dim3(512), 0, stream>>>(A, lda, W, ldw, bias,
                                               C, ldc, Cb, ldcb, m, n, k, flags);
    };

    // --- weight & input conversion ---
    cpad(x, xb, M, 80, 128);
    cpad(enc0_w, enc0_wb, 512, 80, 128);
    cvt_fuse<<<dim3(2097152 / 256), dim3(256), 0, stream>>>(enc_lw, enc_mw, encFW, 2097152);
    bias_fuse<<<dim3(16), dim3(256), 0, stream>>>(enc_lb, enc_mb, encFB, 4096);
    {
        // batched fp32->bf16 conversions (8 jobs, one launch)
        CvtJobs jobs;
        const float* srcs[8] = {spk_emb, spk_w1, spk_w2, spk_w3,
                                tr_in_w, tr_out_w, tr_ff1_w, tr_ff2_w};
        u16t* dsts[8] = {spk_embb, spk_w1b, spk_w2b, spk_w3b,
                         tr_in_wb, tr_out_wb, tr_ff1_wb, tr_ff2_wb};
        const size_t ns[8] = {32 * 192, (size_t)512 * 192, (size_t)512 * 512, (size_t)512 * 512,
                              (size_t)4 * 1536 * 512, (size_t)4 * 512 * 512,
                              (size_t)4 * 2048 * 512, (size_t)4 * 2048 * 512};
        unsigned blk = 0;
        for (int i = 0; i < 8; ++i) {
            jobs.j[i].s = srcs[i];
            jobs.j[i].d = dsts[i];
            jobs.j[i].n8 = (unsigned)(ns[i] / 8);
            jobs.j[i].blk0 = blk;
            blk += (jobs.j[i].n8 + 255) / 256;
        }
        cvt_batch<<<dim3(blk), dim3(256), 0, stream>>>(jobs);
    }
    cpad(adpt_w, adpt_wb, 512, 516, 576);
    cvt_fuse<<<dim3(1572864 / 256), dim3(256), 0, stream>>>(post_lw, post_mw, postFW, 1572864);
    bias_fuse<<<dim3(12), dim3(256), 0, stream>>>(post_lb, post_mb, postFB, 3072);
    cpad(cls_w1, cls_w1b, 512, 512, 512);

    // --- encoder: enc0 writes h into HM0 cols 0-511 ---
    gemm(xb, 128, enc0_wb, 128, enc0_b,
         nullptr, 0, HM0, 1024, M, 512, 128, GB_WB16);
    for (int i = 0; i < 8; ++i) {   // strides 1..128; fused lin+mem GEMM
        u16t* src = HMs[i & 1];
        u16t* dst = HMs[(i + 1) & 1];
        fsmn_means_b<<<dim3(128), dim3(256), 0, stream>>>(src, 1 << i);
        gemm(src, 1024, encFW + (size_t)i * 524288, 1024, encFB + (size_t)i * 512,
             (i == 7 ? H : nullptr), 512, dst, 1024, M, 512, 1024,
             GB_WB16 | (i == 7 ? GB_WF32 : 0));
    }
    // h_enc now in HM0 (+ fp32 copy in H)

    // --- speaker MLP ---
    gemm(spk_embb, 192, spk_w1b, 192, spk_b1,
         nullptr, 0, S1b, 512, 32, 512, 192, GB_RELU | GB_WB16);
    gemm(S1b, 512, spk_w2b, 512, spk_b2,
         nullptr, 0, S2b, 512, 32, 512, 512, GB_RELU | GB_WB16);
    gemm(S2b, 512, spk_w3b, 512, spk_b3,
         S3, 512, nullptr, 0, 32, 512, 512, GB_WF32);

    // --- context-independent scores ---
    ci_kernel<<<dim3(64), dim3(256), 0, stream>>>(HM0, S3, CI);

    // --- transformer (h in HM0 cols 0-511, fp32 residual in H) ---
    for (int i = 0; i < 4; ++i) {
        gemm(HM0, 1024, tr_in_wb + (size_t)i * 786432, 512, tr_in_b + (size_t)i * 1536,
             nullptr, 0, QKVb, 1536, M, 1536, 512, GB_WB16);
        vtprep<<<dim3(32, 32), dim3(256), 0, stream>>>(QKVb, Vt);
        attn_bf16<<<dim3(16, 32), dim3(512), 0, stream>>>(QKVb, Vt, AOb);
        gemm(AOb, 512, tr_out_wb + (size_t)i * 262144, 512, tr_out_b + (size_t)i * 512,
             nullptr, 0, T1b, 512, M, 512, 512, GB_WB16);
        ln_add_f32<<<dim3(M / 4), dim3(256), 0, stream>>>(
            H, T1b, tr_ln1_w + (size_t)i * 512, tr_ln1_b + (size_t)i * 512, H, HM0);
        gemm(HM0, 1024, tr_ff1_wb + (size_t)i * 1048576, 512, tr_ff1_b + (size_t)i * 2048,
             nullptr, 0, Fb, 2048, M, 2048, 512, GB_RELU | GB_WB16);
        gemm(Fb, 2048, tr_ff2_wb + (size_t)i * 1048576, 2048, tr_ff2_b + (size_t)i * 512,
             nullptr, 0, T1b, 512, M, 512, 2048, GB_WB16);
        ln_add_f32<<<dim3(M / 4), dim3(256), 0, stream>>>(
            H, T1b, tr_ln2_w + (size_t)i * 512, tr_ln2_b + (size_t)i * 512, H, HM0);
    }

    // --- concat + adapter ---
    concat_b<<<dim3((unsigned)(((size_t)M * 144 + 255) / 256)), dim3(256), 0, stream>>>(CI, HM0, Xcatb);
    gemm(Xcatb, 576, adpt_wb, 576, adpt_b,
         nullptr, 0, HM0, 1024, M, 512, 576, GB_WB16);

    // --- post FSMN (6 fused layers, strides 1..32) ---
    for (int i = 0; i < 6; ++i) {
        u16t* src = HMs[i & 1];
        u16t* dst = HMs[(i + 1) & 1];
        fsmn_means_b<<<dim3(128), dim3(256), 0, stream>>>(src, 1 << i);
        gemm(src, 1024, postFW + (size_t)i * 524288, 1024, postFB + (size_t)i * 512,
             nullptr, 0, dst, 1024, M, 512, 1024, GB_WB16);
    }
    // result in HM0

    // --- classifier ---
    gemm(HM0, 1024, cls_w1b, 512, cls_b1,
         T1, 512, nullptr, 0, M, 512, 512, GB_RELU | GB_WF32);
    cls2_kernel<<<dim3(M / 16), dim3(256), 0, stream>>>(T1, cls_w2, cls_b2, (float*)d_out);
}

// Round 13
// 3104.288 us; speedup vs baseline: 1.0289x; 1.0289x over previous
//
#include <hip/hip_runtime.h>
#include <hip/hip_bf16.h>
#include <math.h>

typedef unsigned short u16t;
using f32x4 = __attribute__((ext_vector_type(4))) float;
using s16x8 = __attribute__((ext_vector_type(8))) short;
using us8   = __attribute__((ext_vector_type(8))) unsigned short;

#define GB_RELU 1
#define GB_WF32 4
#define GB_WB16 8

__device__ __forceinline__ u16t f2b(float f) {
    unsigned u = __float_as_uint(f);
    unsigned r = (u + 0x7FFFu + ((u >> 16) & 1u)) >> 16;
    return (u16t)r;
}
__device__ __forceinline__ float b2f(u16t s) {
    return __uint_as_float(((unsigned)s) << 16);
}
__device__ __forceinline__ void gload16(const void* gsrc, void* ldst) {
    __builtin_amdgcn_global_load_lds(
        (const __attribute__((address_space(1))) void*)gsrc,
        (__attribute__((address_space(3))) void*)ldst, 16, 0, 0);
}

// ---------------------------------------------------------------------------
// bf16 MFMA GEMM, 2-phase pipelined (counted vmcnt, raw barriers), swizzled
// LDS, XCD-chunked block swizzle, LDS-staged coalesced bf16 epilogue.
// C[M,N] = A[M,K](bf16) @ W[N,K]^T(bf16) + bias; relu opt.
// 128x128 tile, BK=64, 512 thr (8 waves, 2Mx4N), acc[4][2]/wave.
// [round-11 proven: do NOT single-buffer (r12 -3%) or 1-barrier (r8 -7%)]
// ---------------------------------------------------------------------------
__global__ __launch_bounds__(512)
void gemm_bf16(const u16t* __restrict__ A, int lda,
               const u16t* __restrict__ W, int ldw,
               const float* __restrict__ bias,
               float* __restrict__ C, int ldc,
               u16t* __restrict__ Cb, int ldcb,
               int M, int N, int K, int flags)
{
    __shared__ u16t SM[32768];          // 64 KiB: As[2][8192] | Ws[2][8192]
    u16t* As = SM;
    u16t* Ws = SM + 16384;
    const int tid = threadIdx.x;
    const int lane = tid & 63, w = tid >> 6;
    const int wr = w >> 2, wc = w & 3;       // 2M x 4N wave grid
    const int l15 = lane & 15, l4 = lane >> 4;

    // XCD-chunked bijective swizzle (only when nwg % 8 == 0)
    unsigned nwg = gridDim.x * gridDim.y;
    unsigned bid = blockIdx.y * gridDim.x + blockIdx.x;
    if ((nwg & 7u) == 0u) bid = (bid & 7u) * (nwg >> 3) + (bid >> 3);
    const int m0 = (int)(bid / gridDim.x) * 128;
    const int n0 = (int)(bid % gridDim.x) * 128;

    int arow[2], wrow[2], koff[2], se0[2];
#pragma unroll
    for (int it = 0; it < 2; ++it) {
        const int e = it * 512 + tid;          // 16B unit 0..1023
        se0[it] = it * 512 + (tid & 448);      // wave-uniform base
        const int kb = e >> 7, r = e & 127;
        const int rg = r ^ (kb & 3);
        int gm = m0 + rg; if (gm > M - 1) gm = M - 1;
        arow[it] = gm;
        wrow[it] = n0 + rg;
        koff[it] = kb * 8;
    }

    f32x4 acc[4][2];
#pragma unroll
    for (int i = 0; i < 4; ++i)
#pragma unroll
        for (int j = 0; j < 2; ++j) acc[i][j] = (f32x4){0.f, 0.f, 0.f, 0.f};

    auto STAGE = [&](int buf, int k0) {
#pragma unroll
        for (int it = 0; it < 2; ++it)
            gload16(A + (size_t)arow[it] * lda + k0 + koff[it],
                    &As[(size_t)(buf * 8192 + se0[it] * 8)]);
#pragma unroll
        for (int it = 0; it < 2; ++it)
            gload16(W + (size_t)wrow[it] * ldw + k0 + koff[it],
                    &Ws[(size_t)(buf * 8192 + se0[it] * 8)]);
    };

    const int nk = K >> 6;
    STAGE(0, 0);
    for (int ks = 0; ks < nk; ++ks) {
        const int cur = ks & 1;
        if (ks + 1 < nk) {
            STAGE(cur ^ 1, (ks + 1) << 6);
            asm volatile("s_waitcnt vmcnt(4)" ::: "memory");
        } else {
            asm volatile("s_waitcnt vmcnt(0)" ::: "memory");
        }
        __builtin_amdgcn_s_barrier();
#pragma unroll
        for (int kk = 0; kk < 2; ++kk) {
            const int kb = kk * 4 + l4;
            const int ls = l15 ^ l4;     // swizzled row-within-16 on read
            s16x8 a[4], b[2];
#pragma unroll
            for (int mi = 0; mi < 4; ++mi)
                a[mi] = *(const s16x8*)&As[(size_t)(cur * 8192 + (kb * 128 + wr * 64 + mi * 16 + ls) * 8)];
#pragma unroll
            for (int ni = 0; ni < 2; ++ni)
                b[ni] = *(const s16x8*)&Ws[(size_t)(cur * 8192 + (kb * 128 + wc * 32 + ni * 16 + ls) * 8)];
#pragma unroll
            for (int mi = 0; mi < 4; ++mi)
#pragma unroll
                for (int ni = 0; ni < 2; ++ni)
                    acc[mi][ni] = __builtin_amdgcn_mfma_f32_16x16x32_bf16(
                        a[mi], b[ni], acc[mi][ni], 0, 0, 0);
        }
        __builtin_amdgcn_s_barrier();
    }

    // epilogue
    if (flags & GB_WB16) __syncthreads();
#pragma unroll
    for (int mi = 0; mi < 4; ++mi) {
#pragma unroll
        for (int r = 0; r < 4; ++r) {
            const int rowl = wr * 64 + mi * 16 + l4 * 4 + r;
            const int row = m0 + rowl;
            const bool rok = row < M;
#pragma unroll
            for (int ni = 0; ni < 2; ++ni) {
                const int coll = wc * 32 + ni * 16 + l15;
                float v = acc[mi][ni][r];
                if (bias) v += bias[n0 + coll];
                if (flags & GB_RELU) v = fmaxf(v, 0.f);
                if ((flags & GB_WF32) && rok) C[(size_t)row * ldc + n0 + coll] = v;
                if (flags & GB_WB16) SM[rowl * 136 + coll] = f2b(v);
            }
        }
    }
    if (flags & GB_WB16) {
        __syncthreads();
#pragma unroll
        for (int rr = 0; rr < 4; ++rr) {
            const int rowl = rr * 32 + (tid >> 4);
            const int c0 = (tid & 15) * 8;
            if (m0 + rowl < M)
                *(us8*)(Cb + (size_t)(m0 + rowl) * ldcb + n0 + c0) =
                    *(const us8*)&SM[rowl * 136 + c0];
        }
    }
}

// ---------------------------------------------------------------------------
// FSMN sliding-window mean, vectorized (ushort4 = 4 d per thread).
// In-place on HM[M,1024]: reads cols 0-511 (h), writes cols 512-1023.
// grid 128 blocks, 256 thr; each 128-thread group = one (b, 64-row chunk).
// ---------------------------------------------------------------------------
__global__ __launch_bounds__(256)
void fsmn_means_b(u16t* __restrict__ HM, int stride)
{
    const int g = blockIdx.x * 2 + (threadIdx.x >> 7);   // 0..255
    const int t = threadIdx.x & 127;
    const int b = g >> 5, chunk = g & 31;                // 8 b x 32 chunks
    const int c0 = chunk * 64;
    const int d0 = t * 4;
    const u16t* Hp = HM + (size_t)b * 2048 * 1024 + d0;
    u16t* Mp = HM + (size_t)b * 2048 * 1024 + 512 + d0;
    float s0 = 0.f, s1 = 0.f, s2 = 0.f, s3 = 0.f;
    int j0 = c0 - stride; if (j0 < 0) j0 = 0;
    for (int j = j0; j < c0; ++j) {
        const ushort4 hv = *(const ushort4*)(Hp + (size_t)j * 1024);
        s0 += b2f(hv.x); s1 += b2f(hv.y); s2 += b2f(hv.z); s3 += b2f(hv.w);
    }
    for (int i = c0; i < c0 + 64; ++i) {
        const ushort4 hv = *(const ushort4*)(Hp + (size_t)i * 1024);
        s0 += b2f(hv.x); s1 += b2f(hv.y); s2 += b2f(hv.z); s3 += b2f(hv.w);
        const int st = i - stride;
        const float cnt = (float)(i + 1 - (st > 0 ? st : 0));
        ushort4 ov;
        ov.x = f2b(s0 / cnt); ov.y = f2b(s1 / cnt);
        ov.z = f2b(s2 / cnt); ov.w = f2b(s3 / cnt);
        *(ushort4*)(Mp + (size_t)i * 1024) = ov;
        if (st >= 0) {
            const ushort4 hs = *(const ushort4*)(Hp + (size_t)st * 1024);
            s0 -= b2f(hs.x); s1 -= b2f(hs.y); s2 -= b2f(hs.z); s3 -= b2f(hs.w);
        }
    }
}

// ---------------------------------------------------------------------------
// ci[b,l,s] = dot(HM[b,l,0:512], SF[b,s,:]) — one thread per row, all 4 s.
// ---------------------------------------------------------------------------
__global__ __launch_bounds__(256)
void ci_kernel(const u16t* __restrict__ HM, const float* __restrict__ SF,
               float* __restrict__ CI)
{
    const int bl = blockIdx.x * 256 + threadIdx.x;   // 0..16383
    const int b = bl >> 11;
    const us8* h8 = (const us8*)(HM + (size_t)bl * 1024);
    const float4* f4 = (const float4*)(SF + (size_t)b * 4 * 512);
    float a0 = 0.f, a1 = 0.f, a2 = 0.f, a3 = 0.f;
    for (int k = 0; k < 64; ++k) {
        const us8 hv = h8[k];
        float hf[8];
#pragma unroll
        for (int j = 0; j < 8; ++j) hf[j] = b2f(hv[j]);
#pragma unroll
        for (int s = 0; s < 4; ++s) {
            const float4 x = f4[s * 128 + k * 2];
            const float4 y = f4[s * 128 + k * 2 + 1];
            const float d = hf[0] * x.x + hf[1] * x.y + hf[2] * x.z + hf[3] * x.w
                          + hf[4] * y.x + hf[5] * y.y + hf[6] * y.z + hf[7] * y.w;
            if (s == 0) a0 += d; else if (s == 1) a1 += d;
            else if (s == 2) a2 += d; else a3 += d;
        }
    }
    float4 outv = make_float4(a0, a1, a2, a3);
    *(float4*)(CI + (size_t)bl * 4) = outv;
}

// ---------------------------------------------------------------------------
// Y(ld512,f32) = LN(X + Rb) * w + b ; Rb bf16 ld512; Yb(ld1024,bf16).
// ---------------------------------------------------------------------------
__global__ __launch_bounds__(256)
void ln_add_f32(const float* __restrict__ X, const u16t* __restrict__ Rb,
                const float* __restrict__ w, const float* __restrict__ b,
                float* __restrict__ Y, u16t* __restrict__ Yb)
{
    const int lane = threadIdx.x & 63, wid = threadIdx.x >> 6;
    const size_t row = (size_t)blockIdx.x * 4 + wid;
    const float* x = X + row * 512;
    const u16t* r = Rb + row * 512;
    const int c0 = lane * 8;
    float v[8];
    {
        const float4 a0 = *(const float4*)(x + c0);
        const float4 a1 = *(const float4*)(x + c0 + 4);
        const us8 r8 = *(const us8*)(r + c0);
        v[0] = a0.x + b2f(r8[0]); v[1] = a0.y + b2f(r8[1]);
        v[2] = a0.z + b2f(r8[2]); v[3] = a0.w + b2f(r8[3]);
        v[4] = a1.x + b2f(r8[4]); v[5] = a1.y + b2f(r8[5]);
        v[6] = a1.z + b2f(r8[6]); v[7] = a1.w + b2f(r8[7]);
    }
    float s = 0.f;
#pragma unroll
    for (int j = 0; j < 8; ++j) s += v[j];
#pragma unroll
    for (int off = 1; off < 64; off <<= 1) s += __shfl_xor(s, off);
    const float mean = s * (1.f / 512.f);
    float q = 0.f;
#pragma unroll
    for (int j = 0; j < 8; ++j) { const float dd = v[j] - mean; q += dd * dd; }
#pragma unroll
    for (int off = 1; off < 64; off <<= 1) q += __shfl_xor(q, off);
    const float rstd = rsqrtf(q * (1.f / 512.f) + 1e-5f);
    float* y = Y + row * 512;
    u16t* yb = Yb + row * 1024;
#pragma unroll
    for (int j = 0; j < 8; ++j) {
        const float o = (v[j] - mean) * rstd * w[c0 + j] + b[c0 + j];
        y[c0 + j] = o;
        yb[c0 + j] = f2b(o);
    }
}

// ---------------------------------------------------------------------------
// V transpose: Vt[b,h,d,l] (bf16) from QKVb[b,l,1024+h*128+d] (bf16).
// grid (L/64, B*H), block 256.
// ---------------------------------------------------------------------------
__global__ __launch_bounds__(256)
void vtprep(const u16t* __restrict__ QKVb, u16t* __restrict__ Vt)
{
    __shared__ u16t T[128 * 72];
    const int tid = threadIdx.x;
    const int l0 = blockIdx.x * 64;
    const int bh = blockIdx.y, b = bh >> 2, h = bh & 3;
#pragma unroll
    for (int it = 0; it < 4; ++it) {
        const int e = it * 256 + tid;
        const int l = e >> 4, dc = e & 15;
        const us8 v = *(const us8*)(QKVb + ((size_t)(b * 2048 + l0 + l)) * 1536
                                   + 1024 + h * 128 + dc * 8);
#pragma unroll
        for (int j = 0; j < 8; ++j) T[(dc * 8 + j) * 72 + l] = v[j];
    }
    __syncthreads();
#pragma unroll
    for (int it = 0; it < 4; ++it) {
        const int e = it * 256 + tid;
        const int d = e >> 3, lc = e & 7;
        const us8 ov = *(const us8*)&T[d * 72 + lc * 8];
        *(us8*)(Vt + ((size_t)bh * 128 + d) * 2048 + l0 + lc * 8) = ov;
    }
}

// ---------------------------------------------------------------------------
// MFMA flash attention, 2-phase pipelined (counted vmcnt), defer-max THR=8,
// grid (16, 32) = 512 blocks, 512 thr. XCD-grouped (b,h).  [round-7 proven]
// ---------------------------------------------------------------------------
__global__ __launch_bounds__(512)
void attn_bf16(const u16t* __restrict__ QKVb, const u16t* __restrict__ Vt,
               u16t* __restrict__ AOb)
{
    __shared__ u16t Kt[2][8192];
    __shared__ u16t Vtl[2][8192];
    __shared__ u16t Pl[8192];
    const int tid = threadIdx.x, lane = tid & 63, w = tid >> 6;
    const int l15 = lane & 15, l4 = lane >> 4;
    const unsigned bid = blockIdx.y * gridDim.x + blockIdx.x;  // 0..511
    const int xcd = bid & 7, idx = bid >> 3;
    const int bh = xcd * 4 + (idx & 3);
    const int q0 = (idx >> 2) * 128;
    const int b = bh >> 2, h = bh & 3;
    const float SCALE = 0.08838834764831845f;   // 1/sqrt(128)

    int krow[2], kdoff[2], vd[2], vkoff[2], se0[2];
#pragma unroll
    for (int it = 0; it < 2; ++it) {
        const int e = it * 512 + tid;
        se0[it] = it * 512 + (tid & 448);
        const int dblk = e >> 6, key = e & 63;
        krow[it] = key ^ (dblk & 3);
        kdoff[it] = dblk * 8;
        const int kb = e >> 7, d = e & 127;
        vd[it] = d ^ (kb & 3);
        vkoff[it] = kb * 8;
    }
    auto STAGE = [&](int buf, int k0) {
#pragma unroll
        for (int it = 0; it < 2; ++it)
            gload16(QKVb + ((size_t)(b * 2048 + k0 + krow[it])) * 1536 + 512 + h * 128 + kdoff[it],
                    &Kt[buf][(size_t)se0[it] * 8]);
#pragma unroll
        for (int it = 0; it < 2; ++it)
            gload16(Vt + ((size_t)bh * 128 + vd[it]) * 2048 + k0 + vkoff[it],
                    &Vtl[buf][(size_t)se0[it] * 8]);
    };

    s16x8 qf[4];
    {
        const u16t* qp = QKVb + ((size_t)(b * 2048 + q0 + w * 16 + l15)) * 1536
                         + h * 128 + l4 * 8;
#pragma unroll
        for (int ks = 0; ks < 4; ++ks) qf[ks] = *(const s16x8*)(qp + ks * 32);
    }
    asm volatile("s_waitcnt vmcnt(0)" ::: "memory");

    f32x4 o[8];
#pragma unroll
    for (int i = 0; i < 8; ++i) o[i] = (f32x4){0.f, 0.f, 0.f, 0.f};
    f32x4 m_run, lsum;
#pragma unroll
    for (int r = 0; r < 4; ++r) { m_run[r] = -1e30f; lsum[r] = 0.f; }

    const int ls = l15 ^ l4;
    STAGE(0, 0);
    for (int kt = 0; kt < 32; ++kt) {
        const int cur = kt & 1;
        if (kt + 1 < 32) {
            STAGE(cur ^ 1, (kt + 1) * 64);
            asm volatile("s_waitcnt vmcnt(4)" ::: "memory");
        } else {
            asm volatile("s_waitcnt vmcnt(0)" ::: "memory");
        }
        __builtin_amdgcn_s_barrier();

        f32x4 s[4];
#pragma unroll
        for (int ni = 0; ni < 4; ++ni) s[ni] = (f32x4){0.f, 0.f, 0.f, 0.f};
#pragma unroll
        for (int ks = 0; ks < 4; ++ks) {
#pragma unroll
            for (int ni = 0; ni < 4; ++ni) {
                const s16x8 kf = *(const s16x8*)&Kt[cur][(size_t)((ks * 4 + l4) * 64 + ni * 16 + ls) * 8];
                s[ni] = __builtin_amdgcn_mfma_f32_16x16x32_bf16(qf[ks], kf, s[ni], 0, 0, 0);
            }
        }
        f32x4 mx;
#pragma unroll
        for (int r = 0; r < 4; ++r)
            mx[r] = fmaxf(fmaxf(s[0][r], s[1][r]), fmaxf(s[2][r], s[3][r])) * SCALE;
#pragma unroll
        for (int off = 1; off < 16; off <<= 1)
#pragma unroll
            for (int r = 0; r < 4; ++r) mx[r] = fmaxf(mx[r], __shfl_xor(mx[r], off));
        bool small = true;
#pragma unroll
        for (int r = 0; r < 4; ++r) small = small && (mx[r] <= m_run[r] + 8.f);
        if (!__all(small)) {
            f32x4 corr;
#pragma unroll
            for (int r = 0; r < 4; ++r) {
                const float nm = fmaxf(m_run[r], mx[r]);
                corr[r] = __expf(m_run[r] - nm);
                m_run[r] = nm;
                lsum[r] *= corr[r];
            }
#pragma unroll
            for (int ni = 0; ni < 8; ++ni)
#pragma unroll
                for (int r = 0; r < 4; ++r) o[ni][r] *= corr[r];
        }
        float p[4][4];
#pragma unroll
        for (int ni = 0; ni < 4; ++ni)
#pragma unroll
            for (int r = 0; r < 4; ++r) {
                p[ni][r] = __expf(s[ni][r] * SCALE - m_run[r]);
                lsum[r] += p[ni][r];
            }
#pragma unroll
        for (int ni = 0; ni < 4; ++ni) {
            const int key = ni * 16 + l15;
            const int kb = key >> 3, kj = key & 7;
#pragma unroll
            for (int r = 0; r < 4; ++r)
                Pl[(size_t)((w * 8 + kb) * 16 + l4 * 4 + r) * 8 + kj] = f2b(p[ni][r]);
        }
#pragma unroll
        for (int kk = 0; kk < 2; ++kk) {
            const s16x8 pa = *(const s16x8*)&Pl[(size_t)((w * 8 + kk * 4 + l4) * 16 + l15) * 8];
#pragma unroll
            for (int ni = 0; ni < 8; ++ni) {
                const s16x8 vf = *(const s16x8*)&Vtl[cur][(size_t)((kk * 4 + l4) * 128 + ni * 16 + ls) * 8];
                o[ni] = __builtin_amdgcn_mfma_f32_16x16x32_bf16(pa, vf, o[ni], 0, 0, 0);
            }
        }
        __builtin_amdgcn_s_barrier();
    }
#pragma unroll
    for (int off = 1; off < 16; off <<= 1)
#pragma unroll
        for (int r = 0; r < 4; ++r) lsum[r] += __shfl_xor(lsum[r], off);
    f32x4 inv;
#pragma unroll
    for (int r = 0; r < 4; ++r) inv[r] = 1.f / lsum[r];
#pragma unroll
    for (int ni = 0; ni < 8; ++ni)
#pragma unroll
        for (int r = 0; r < 4; ++r)
            AOb[((size_t)(b * 2048 + q0 + w * 16 + l4 * 4 + r)) * 512
                + h * 128 + ni * 16 + l15] = f2b(o[ni][r] * inv[r]);
}

// ---------------------------------------------------------------------------
// concat -> padded bf16 [M,576], vectorized (4-col groups; 576 = 144*4).
// ---------------------------------------------------------------------------
__global__ __launch_bounds__(256)
void concat_b(const float* __restrict__ CI, const u16t* __restrict__ HM,
              u16t* __restrict__ OUTC)
{
    const size_t total = (size_t)16384 * 144;
    const size_t i = (size_t)blockIdx.x * 256 + threadIdx.x;
    if (i >= total) return;
    const int gcol = (int)(i % 144);
    const size_t row = i / 144;
    ushort4 v;
    if (gcol == 0) {
        const float4 c = *(const float4*)(CI + row * 4);
        v.x = f2b(c.x); v.y = f2b(c.y); v.z = f2b(c.z); v.w = f2b(c.w);
    } else if (gcol < 129) {
        v = *(const ushort4*)(HM + row * 1024 + (size_t)(gcol - 1) * 4);
    } else {
        v.x = 0; v.y = 0; v.z = 0; v.w = 0;
    }
    *(ushort4*)(OUTC + row * 576 + (size_t)gcol * 4) = v;
}

// ---------------------------------------------------------------------------
// converters
// ---------------------------------------------------------------------------
struct CvtJob { const float* s; u16t* d; unsigned n8; unsigned blk0; };
struct CvtJobs { CvtJob j[8]; };

__global__ __launch_bounds__(256)
void cvt_batch(CvtJobs jobs)
{
    int lo = 0;
#pragma unroll
    for (int i = 1; i < 8; ++i) if (blockIdx.x >= jobs.j[i].blk0) lo = i;
    const float* src = jobs.j[lo].s;
    u16t* dst = jobs.j[lo].d;
    const size_t i = (size_t)(blockIdx.x - jobs.j[lo].blk0) * 256 + threadIdx.x;
    if (i >= jobs.j[lo].n8) return;
    const float4 a = ((const float4*)src)[i * 2];
    const float4 b = ((const float4*)src)[i * 2 + 1];
    us8 o;
    o[0] = f2b(a.x); o[1] = f2b(a.y); o[2] = f2b(a.z); o[3] = f2b(a.w);
    o[4] = f2b(b.x); o[5] = f2b(b.y); o[6] = f2b(b.z); o[7] = f2b(b.w);
    ((us8*)dst)[i] = o;
}

// generic pad (scalar) — only for sc not divisible by 8 (adapter 516->576)
__global__ __launch_bounds__(256)
void cvt_pad(const float* __restrict__ src, u16t* __restrict__ dst,
             int rows, int sc, int dc)
{
    const size_t i = (size_t)blockIdx.x * 256 + threadIdx.x;
    const size_t total = (size_t)rows * dc;
    if (i >= total) return;
    const int c = (int)(i % dc);
    const size_t r = i / dc;
    dst[i] = (c < sc) ? f2b(src[r * sc + c]) : (u16t)0;
}

// vectorized pad for 8-aligned sc/dc (x: 80->128, enc0_w: 80->128)
__global__ __launch_bounds__(256)
void cvt_pad8(const float* __restrict__ src, u16t* __restrict__ dst,
              int rows, int sc, int dc)
{
    const int gpr = dc >> 3;
    const size_t total = (size_t)rows * gpr;
    const size_t i = (size_t)blockIdx.x * 256 + threadIdx.x;
    if (i >= total) return;
    const int g = (int)(i % gpr);
    const size_t r = i / gpr;
    us8 o;
    if (g * 8 < sc) {
        const float* p = src + r * sc + g * 8;
        const float4 a = *(const float4*)p;
        const float4 b = *(const float4*)(p + 4);
        o[0] = f2b(a.x); o[1] = f2b(a.y); o[2] = f2b(a.z); o[3] = f2b(a.w);
        o[4] = f2b(b.x); o[5] = f2b(b.y); o[6] = f2b(b.z); o[7] = f2b(b.w);
    } else {
        o[0] = 0; o[1] = 0; o[2] = 0; o[3] = 0;
        o[4] = 0; o[5] = 0; o[6] = 0; o[7] = 0;
    }
    *(us8*)(dst + r * dc + g * 8) = o;
}

// fuse [layers,512,512] lw,mw -> [layers,512,1024], vectorized 8 elems/thread
__global__ __launch_bounds__(256)
void cvt_fuse(const float* __restrict__ lsrc, const float* __restrict__ msrc,
              u16t* __restrict__ dst, int n8)
{
    const int idx = blockIdx.x * 256 + threadIdx.x;
    if (idx >= n8) return;
    const int k8 = idx & 63;              // 64 groups of 8 per 512-col row
    const int nn = (idx >> 6) & 511;
    const int i = idx >> 15;
    const size_t sbase = (size_t)i * 262144 + (size_t)nn * 512 + (size_t)k8 * 8;
    const size_t dbase = (size_t)i * 524288 + (size_t)nn * 1024 + (size_t)k8 * 8;
    {
        const float4 a = *(const float4*)(lsrc + sbase);
        const float4 b = *(const float4*)(lsrc + sbase + 4);
        us8 o;
        o[0] = f2b(a.x); o[1] = f2b(a.y); o[2] = f2b(a.z); o[3] = f2b(a.w);
        o[4] = f2b(b.x); o[5] = f2b(b.y); o[6] = f2b(b.z); o[7] = f2b(b.w);
        *(us8*)(dst + dbase) = o;
    }
    {
        const float4 a = *(const float4*)(msrc + sbase);
        const float4 b = *(const float4*)(msrc + sbase + 4);
        us8 o;
        o[0] = f2b(a.x); o[1] = f2b(a.y); o[2] = f2b(a.z); o[3] = f2b(a.w);
        o[4] = f2b(b.x); o[5] = f2b(b.y); o[6] = f2b(b.z); o[7] = f2b(b.w);
        *(us8*)(dst + dbase + 512) = o;
    }
}

__global__ __launch_bounds__(256)
void bias_fuse(const float* __restrict__ a, const float* __restrict__ b,
               float* __restrict__ dst, int n)
{
    const int i = blockIdx.x * 256 + threadIdx.x;
    if (i < n) dst[i] = a[i] + b[i];
}

// ---------------------------------------------------------------------------
// final tiny GEMM: out[M,16] = T1[M,512] @ W2[16,512]^T + b2   (fp32)
// ---------------------------------------------------------------------------
__global__ __launch_bounds__(256)
void cls2_kernel(const float* __restrict__ T1, const float* __restrict__ W2,
                 const float* __restrict__ b2, float* __restrict__ out)
{
    const int t = threadIdx.x;
    const int r = blockIdx.x * 16 + (t >> 4), c = t & 15;
    const float4* a = (const float4*)(T1 + (size_t)r * 512);
    const float4* wv = (const float4*)(W2 + (size_t)c * 512);
    float acc = 0.f;
    for (int k = 0; k < 128; ++k) {
        const float4 x = a[k], y = wv[k];
        acc += x.x * y.x + x.y * y.y + x.z * y.z + x.w * y.w;
    }
    out[(size_t)r * 16 + c] = acc + b2[c];
}

// ---------------------------------------------------------------------------
extern "C" void kernel_launch(void* const* d_in, const int* in_sizes, int n_in,
                              void* d_out, int out_size, void* d_ws, size_t ws_size,
                              hipStream_t stream)
{
    (void)in_sizes; (void)n_in; (void)out_size; (void)ws_size;
    const int M = 16384;   // B*L

    const float* x        = (const float*)d_in[0];
    const float* spk_emb  = (const float*)d_in[1];
    const float* enc0_w   = (const float*)d_in[2];
    const float* enc0_b   = (const float*)d_in[3];
    const float* enc_lw   = (const float*)d_in[4];
    const float* enc_lb   = (const float*)d_in[5];
    const float* enc_mw   = (const float*)d_in[6];
    const float* enc_mb   = (const float*)d_in[7];
    const float* spk_w1   = (const float*)d_in[8];
    const float* spk_b1   = (const float*)d_in[9];
    const float* spk_w2   = (const float*)d_in[10];
    const float* spk_b2   = (const float*)d_in[11];
    const float* spk_w3   = (const float*)d_in[12];
    const float* spk_b3   = (const float*)d_in[13];
    const float* tr_in_w  = (const float*)d_in[14];
    const float* tr_in_b  = (const float*)d_in[15];
    const float* tr_out_w = (const float*)d_in[16];
    const float* tr_out_b = (const float*)d_in[17];
    const float* tr_ln1_w = (const float*)d_in[18];
    const float* tr_ln1_b = (const float*)d_in[19];
    const float* tr_ff1_w = (const float*)d_in[20];
    const float* tr_ff1_b = (const float*)d_in[21];
    const float* tr_ff2_w = (const float*)d_in[22];
    const float* tr_ff2_b = (const float*)d_in[23];
    const float* tr_ln2_w = (const float*)d_in[24];
    const float* tr_ln2_b = (const float*)d_in[25];
    const float* adpt_w   = (const float*)d_in[26];
    const float* adpt_b   = (const float*)d_in[27];
    const float* post_lw  = (const float*)d_in[28];
    const float* post_lb  = (const float*)d_in[29];
    const float* post_mw  = (const float*)d_in[30];
    const float* post_mb  = (const float*)d_in[31];
    const float* cls_w1   = (const float*)d_in[32];
    const float* cls_b1   = (const float*)d_in[33];
    const float* cls_w2   = (const float*)d_in[34];
    const float* cls_b2   = (const float*)d_in[35];

    // ---- workspace layout ----
    char* wsp = (char*)d_ws;
    size_t off = 0;
    auto alloc = [&](size_t bytes) -> void* {
        void* p = wsp + off; off += (bytes + 255) & ~(size_t)255; return p;
    };
    float* H    = (float*)alloc((size_t)M * 512 * 4);      // fp32 residual stream
    float* T1   = (float*)alloc((size_t)M * 512 * 4);      // fp32 temp (cls1) / T1b
    u16t*  HM0  = (u16t*) alloc((size_t)M * 1024 * 2);     // [h | means] ping
    u16t*  AOb  = (u16t*) alloc((size_t)M * 512 * 2);      // attn out
    u16t*  BIG  = (u16t*) alloc((size_t)M * 2048 * 2);     // HM1 | xb | QKV+Vt | F | Xcat
    float* CI   = (float*)alloc((size_t)M * 4 * 4);
    float* S3   = (float*)alloc(32 * 512 * 4);
    u16t* enc0_wb   = (u16t*)alloc(512 * 128 * 2);
    u16t* encFW     = (u16t*)alloc((size_t)8 * 512 * 1024 * 2);
    float* encFB    = (float*)alloc(8 * 512 * 4);
    u16t* spk_embb  = (u16t*)alloc(32 * 192 * 2);
    u16t* spk_w1b   = (u16t*)alloc(512 * 192 * 2);
    u16t* spk_w2b   = (u16t*)alloc(512 * 512 * 2);
    u16t* spk_w3b   = (u16t*)alloc(512 * 512 * 2);
    u16t* tr_in_wb  = (u16t*)alloc((size_t)4 * 1536 * 512 * 2);
    u16t* tr_out_wb = (u16t*)alloc((size_t)4 * 512 * 512 * 2);
    u16t* tr_ff1_wb = (u16t*)alloc((size_t)4 * 2048 * 512 * 2);
    u16t* tr_ff2_wb = (u16t*)alloc((size_t)4 * 2048 * 512 * 2);
    u16t* adpt_wb   = (u16t*)alloc(512 * 576 * 2);
    u16t* postFW    = (u16t*)alloc((size_t)6 * 512 * 1024 * 2);
    float* postFB   = (float*)alloc(6 * 512 * 4);
    u16t* cls_w1b   = (u16t*)alloc(512 * 512 * 2);
    u16t* S1b       = (u16t*)alloc(32 * 512 * 2);
    u16t* S2b       = (u16t*)alloc(32 * 512 * 2);

    u16t* HM1   = BIG;                       // [M,1024] during FSMN phases
    u16t* xb    = BIG;                       // [M,128] before enc0 only
    u16t* QKVb  = BIG;                       // [M,1536] during transformer
    u16t* Vt    = BIG + (size_t)M * 1536;    // [B*H,128,2048]
    u16t* Fb    = BIG;                       // [M,2048] FFN hidden
    u16t* Xcatb = BIG;                       // [M,576] concat
    u16t* T1b   = (u16t*)T1;                 // bf16 LN-residual (aliases T1)
    u16t* HMs[2] = {HM0, HM1};

    // 13 params: A,lda, W,ldw, bias, C,ldc, Cb,ldcb, m,n,k, flags
    auto gemm = [&](const u16t* A, int lda, const u16t* W, int ldw,
                    const float* bias, float* C, int ldc, u16t* Cb, int ldcb,
                    int m, int n, int k, int flags) {
        dim3 g(n / 128, (m + 127) / 128);
        gemm_bf16<<<g, dim3(512), 0, stream>>>(A, lda, W, ldw, bias,
                                               C, ldc, Cb, ldcb, m, n, k, flags);
    };

    // --- weight & input conversion ---
    cvt_pad8<<<dim3((unsigned)(((size_t)M * 16 + 255) / 256)), dim3(256), 0, stream>>>(
        x, xb, M, 80, 128);
    cvt_pad8<<<dim3((512 * 16 + 255) / 256), dim3(256), 0, stream>>>(
        enc0_w, enc0_wb, 512, 80, 128);
    cvt_fuse<<<dim3(262144 / 256), dim3(256), 0, stream>>>(enc_lw, enc_mw, encFW, 262144);
    bias_fuse<<<dim3(16), dim3(256), 0, stream>>>(enc_lb, enc_mb, encFB, 4096);
    {
        // batched fp32->bf16 conversions (8 jobs, one launch)
        CvtJobs jobs;
        const float* srcs[8] = {spk_emb, spk_w1, spk_w2, spk_w3,
                                tr_in_w, tr_out_w, tr_ff1_w, tr_ff2_w};
        u16t* dsts[8] = {spk_embb, spk_w1b, spk_w2b, spk_w3b,
                         tr_in_wb, tr_out_wb, tr_ff1_wb, tr_ff2_wb};
        const size_t ns[8] = {32 * 192, (size_t)512 * 192, (size_t)512 * 512, (size_t)512 * 512,
                              (size_t)4 * 1536 * 512, (size_t)4 * 512 * 512,
                              (size_t)4 * 2048 * 512, (size_t)4 * 2048 * 512};
        unsigned blk = 0;
        for (int i = 0; i < 8; ++i) {
            jobs.j[i].s = srcs[i];
            jobs.j[i].d = dsts[i];
            jobs.j[i].n8 = (unsigned)(ns[i] / 8);
            jobs.j[i].blk0 = blk;
            blk += (jobs.j[i].n8 + 255) / 256;
        }
        cvt_batch<<<dim3(blk), dim3(256), 0, stream>>>(jobs);
    }
    cvt_pad<<<dim3((unsigned)(((size_t)512 * 576 + 255) / 256)), dim3(256), 0, stream>>>(
        adpt_w, adpt_wb, 512, 516, 576);
    cvt_fuse<<<dim3(196608 / 256), dim3(256), 0, stream>>>(post_lw, post_mw, postFW, 196608);
    bias_fuse<<<dim3(12), dim3(256), 0, stream>>>(post_lb, post_mb, postFB, 3072);
    cvt_pad8<<<dim3((512 * 64 + 255) / 256), dim3(256), 0, stream>>>(
        cls_w1, cls_w1b, 512, 512, 512);

    // --- encoder: enc0 writes h into HM0 cols 0-511 ---
    gemm(xb, 128, enc0_wb, 128, enc0_b,
         nullptr, 0, HM0, 1024, M, 512, 128, GB_WB16);
    for (int i = 0; i < 8; ++i) {   // strides 1..128; fused lin+mem GEMM
        u16t* src = HMs[i & 1];
        u16t* dst = HMs[(i + 1) & 1];
        fsmn_means_b<<<dim3(128), dim3(256), 0, stream>>>(src, 1 << i);
        gemm(src, 1024, encFW + (size_t)i * 524288, 1024, encFB + (size_t)i * 512,
             (i == 7 ? H : nullptr), 512, dst, 1024, M, 512, 1024,
             GB_WB16 | (i == 7 ? GB_WF32 : 0));
    }
    // h_enc now in HM0 (+ fp32 copy in H)

    // --- speaker MLP ---
    gemm(spk_embb, 192, spk_w1b, 192, spk_b1,
         nullptr, 0, S1b, 512, 32, 512, 192, GB_RELU | GB_WB16);
    gemm(S1b, 512, spk_w2b, 512, spk_b2,
         nullptr, 0, S2b, 512, 32, 512, 512, GB_RELU | GB_WB16);
    gemm(S2b, 512, spk_w3b, 512, spk_b3,
         S3, 512, nullptr, 0, 32, 512, 512, GB_WF32);

    // --- context-independent scores ---
    ci_kernel<<<dim3(64), dim3(256), 0, stream>>>(HM0, S3, CI);

    // --- transformer (h in HM0 cols 0-511, fp32 residual in H) ---
    for (int i = 0; i < 4; ++i) {
        gemm(HM0, 1024, tr_in_wb + (size_t)i * 786432, 512, tr_in_b + (size_t)i * 1536,
             nullptr, 0, QKVb, 1536, M, 1536, 512, GB_WB16);
        vtprep<<<dim3(32, 32), dim3(256), 0, stream>>>(QKVb, Vt);
        attn_bf16<<<dim3(16, 32), dim3(512), 0, stream>>>(QKVb, Vt, AOb);
        gemm(AOb, 512, tr_out_wb + (size_t)i * 262144, 512, tr_out_b + (size_t)i * 512,
             nullptr, 0, T1b, 512, M, 512, 512, GB_WB16);
        ln_add_f32<<<dim3(M / 4), dim3(256), 0, stream>>>(
            H, T1b, tr_ln1_w + (size_t)i * 512, tr_ln1_b + (size_t)i * 512, H, HM0);
        gemm(HM0, 1024, tr_ff1_wb + (size_t)i * 1048576, 512, tr_ff1_b + (size_t)i * 2048,
             nullptr, 0, Fb, 2048, M, 2048, 512, GB_RELU | GB_WB16);
        gemm(Fb, 2048, tr_ff2_wb + (size_t)i * 1048576, 2048, tr_ff2_b + (size_t)i * 512,
             nullptr, 0, T1b, 512, M, 512, 2048, GB_WB16);
        ln_add_f32<<<dim3(M / 4), dim3(256), 0, stream>>>(
            H, T1b, tr_ln2_w + (size_t)i * 512, tr_ln2_b + (size_t)i * 512, H, HM0);
    }

    // --- concat + adapter ---
    concat_b<<<dim3((unsigned)(((size_t)M * 144 + 255) / 256)), dim3(256), 0, stream>>>(CI, HM0, Xcatb);
    gemm(Xcatb, 576, adpt_wb, 576, adpt_b,
         nullptr, 0, HM0, 1024, M, 512, 576, GB_WB16);

    // --- post FSMN (6 fused layers, strides 1..32) ---
    for (int i = 0; i < 6; ++i) {
        u16t* src = HMs[i & 1];
        u16t* dst = HMs[(i + 1) & 1];
        fsmn_means_b<<<dim3(128), dim3(256), 0, stream>>>(src, 1 << i);
        gemm(src, 1024, postFW + (size_t)i * 524288, 1024, postFB + (size_t)i * 512,
             nullptr, 0, dst, 1024, M, 512, 1024, GB_WB16);
    }
    // result in HM0

    // --- classifier ---
    gemm(HM0, 1024, cls_w1b, 512, cls_b1,
         T1, 512, nullptr, 0, M, 512, 512, GB_RELU | GB_WF32);
    cls2_kernel<<<dim3(M / 16), dim3(256), 0, stream>>>(T1, cls_w2, cls_b2, (float*)d_out);
}

// Round 14
// 3002.882 us; speedup vs baseline: 1.0636x; 1.0338x over previous
//
#include <hip/hip_runtime.h>
#include <hip/hip_bf16.h>
#include <math.h>

typedef unsigned short u16t;
using f32x4 = __attribute__((ext_vector_type(4))) float;
using s16x8 = __attribute__((ext_vector_type(8))) short;
using us8   = __attribute__((ext_vector_type(8))) unsigned short;

#define GB_RELU 1
#define GB_WF32 4
#define GB_WB16 8

__device__ __forceinline__ u16t f2b(float f) {
    unsigned u = __float_as_uint(f);
    unsigned r = (u + 0x7FFFu + ((u >> 16) & 1u)) >> 16;
    return (u16t)r;
}
__device__ __forceinline__ float b2f(u16t s) {
    return __uint_as_float(((unsigned)s) << 16);
}
__device__ __forceinline__ void gload16(const void* gsrc, void* ldst) {
    __builtin_amdgcn_global_load_lds(
        (const __attribute__((address_space(1))) void*)gsrc,
        (__attribute__((address_space(3))) void*)ldst, 16, 0, 0);
}

// ---------------------------------------------------------------------------
// bf16 MFMA GEMM, 2-phase pipelined (counted vmcnt, raw barriers), swizzled
// LDS, XCD-chunked block swizzle, LDS-staged coalesced bf16 epilogue.
// C[M,N] = A[M,K](bf16) @ W[N,K]^T(bf16) + bias; relu opt.
// 128x128 tile, BK=64, 512 thr (8 waves, 2Mx4N), acc[4][2]/wave.
// [round-11 proven: do NOT single-buffer (r12 -3%) or 1-barrier (r8 -7%)]
// ---------------------------------------------------------------------------
__global__ __launch_bounds__(512)
void gemm_bf16(const u16t* __restrict__ A, int lda,
               const u16t* __restrict__ W, int ldw,
               const float* __restrict__ bias,
               float* __restrict__ C, int ldc,
               u16t* __restrict__ Cb, int ldcb,
               int M, int N, int K, int flags)
{
    __shared__ u16t SM[32768];          // 64 KiB: As[2][8192] | Ws[2][8192]
    u16t* As = SM;
    u16t* Ws = SM + 16384;
    const int tid = threadIdx.x;
    const int lane = tid & 63, w = tid >> 6;
    const int wr = w >> 2, wc = w & 3;       // 2M x 4N wave grid
    const int l15 = lane & 15, l4 = lane >> 4;

    // XCD-chunked bijective swizzle (only when nwg % 8 == 0)
    unsigned nwg = gridDim.x * gridDim.y;
    unsigned bid = blockIdx.y * gridDim.x + blockIdx.x;
    if ((nwg & 7u) == 0u) bid = (bid & 7u) * (nwg >> 3) + (bid >> 3);
    const int m0 = (int)(bid / gridDim.x) * 128;
    const int n0 = (int)(bid % gridDim.x) * 128;

    int arow[2], wrow[2], koff[2], se0[2];
#pragma unroll
    for (int it = 0; it < 2; ++it) {
        const int e = it * 512 + tid;          // 16B unit 0..1023
        se0[it] = it * 512 + (tid & 448);      // wave-uniform base
        const int kb = e >> 7, r = e & 127;
        const int rg = r ^ (kb & 3);
        int gm = m0 + rg; if (gm > M - 1) gm = M - 1;
        arow[it] = gm;
        wrow[it] = n0 + rg;
        koff[it] = kb * 8;
    }

    f32x4 acc[4][2];
#pragma unroll
    for (int i = 0; i < 4; ++i)
#pragma unroll
        for (int j = 0; j < 2; ++j) acc[i][j] = (f32x4){0.f, 0.f, 0.f, 0.f};

    auto STAGE = [&](int buf, int k0) {
#pragma unroll
        for (int it = 0; it < 2; ++it)
            gload16(A + (size_t)arow[it] * lda + k0 + koff[it],
                    &As[(size_t)(buf * 8192 + se0[it] * 8)]);
#pragma unroll
        for (int it = 0; it < 2; ++it)
            gload16(W + (size_t)wrow[it] * ldw + k0 + koff[it],
                    &Ws[(size_t)(buf * 8192 + se0[it] * 8)]);
    };

    const int nk = K >> 6;
    STAGE(0, 0);
    for (int ks = 0; ks < nk; ++ks) {
        const int cur = ks & 1;
        if (ks + 1 < nk) {
            STAGE(cur ^ 1, (ks + 1) << 6);
            asm volatile("s_waitcnt vmcnt(4)" ::: "memory");
        } else {
            asm volatile("s_waitcnt vmcnt(0)" ::: "memory");
        }
        __builtin_amdgcn_s_barrier();
#pragma unroll
        for (int kk = 0; kk < 2; ++kk) {
            const int kb = kk * 4 + l4;
            const int ls = l15 ^ l4;     // swizzled row-within-16 on read
            s16x8 a[4], b[2];
#pragma unroll
            for (int mi = 0; mi < 4; ++mi)
                a[mi] = *(const s16x8*)&As[(size_t)(cur * 8192 + (kb * 128 + wr * 64 + mi * 16 + ls) * 8)];
#pragma unroll
            for (int ni = 0; ni < 2; ++ni)
                b[ni] = *(const s16x8*)&Ws[(size_t)(cur * 8192 + (kb * 128 + wc * 32 + ni * 16 + ls) * 8)];
#pragma unroll
            for (int mi = 0; mi < 4; ++mi)
#pragma unroll
                for (int ni = 0; ni < 2; ++ni)
                    acc[mi][ni] = __builtin_amdgcn_mfma_f32_16x16x32_bf16(
                        a[mi], b[ni], acc[mi][ni], 0, 0, 0);
        }
        __builtin_amdgcn_s_barrier();
    }

    // epilogue
    if (flags & GB_WB16) __syncthreads();
#pragma unroll
    for (int mi = 0; mi < 4; ++mi) {
#pragma unroll
        for (int r = 0; r < 4; ++r) {
            const int rowl = wr * 64 + mi * 16 + l4 * 4 + r;
            const int row = m0 + rowl;
            const bool rok = row < M;
#pragma unroll
            for (int ni = 0; ni < 2; ++ni) {
                const int coll = wc * 32 + ni * 16 + l15;
                float v = acc[mi][ni][r];
                if (bias) v += bias[n0 + coll];
                if (flags & GB_RELU) v = fmaxf(v, 0.f);
                if ((flags & GB_WF32) && rok) C[(size_t)row * ldc + n0 + coll] = v;
                if (flags & GB_WB16) SM[rowl * 136 + coll] = f2b(v);
            }
        }
    }
    if (flags & GB_WB16) {
        __syncthreads();
#pragma unroll
        for (int rr = 0; rr < 4; ++rr) {
            const int rowl = rr * 32 + (tid >> 4);
            const int c0 = (tid & 15) * 8;
            if (m0 + rowl < M)
                *(us8*)(Cb + (size_t)(m0 + rowl) * ldcb + n0 + c0) =
                    *(const us8*)&SM[rowl * 136 + c0];
        }
    }
}

// ---------------------------------------------------------------------------
// FSMN sliding-window mean, vectorized (ushort4 = 4 d per thread).
// In-place on HM[M,1024]: reads cols 0-511 (h), writes cols 512-1023.
// grid 128 blocks, 256 thr; each 128-thread group = one (b, 64-row chunk).
// ---------------------------------------------------------------------------
__global__ __launch_bounds__(256)
void fsmn_means_b(u16t* __restrict__ HM, int stride)
{
    const int g = blockIdx.x * 2 + (threadIdx.x >> 7);   // 0..255
    const int t = threadIdx.x & 127;
    const int b = g >> 5, chunk = g & 31;                // 8 b x 32 chunks
    const int c0 = chunk * 64;
    const int d0 = t * 4;
    const u16t* Hp = HM + (size_t)b * 2048 * 1024 + d0;
    u16t* Mp = HM + (size_t)b * 2048 * 1024 + 512 + d0;
    float s0 = 0.f, s1 = 0.f, s2 = 0.f, s3 = 0.f;
    int j0 = c0 - stride; if (j0 < 0) j0 = 0;
    for (int j = j0; j < c0; ++j) {
        const ushort4 hv = *(const ushort4*)(Hp + (size_t)j * 1024);
        s0 += b2f(hv.x); s1 += b2f(hv.y); s2 += b2f(hv.z); s3 += b2f(hv.w);
    }
    for (int i = c0; i < c0 + 64; ++i) {
        const ushort4 hv = *(const ushort4*)(Hp + (size_t)i * 1024);
        s0 += b2f(hv.x); s1 += b2f(hv.y); s2 += b2f(hv.z); s3 += b2f(hv.w);
        const int st = i - stride;
        const float cnt = (float)(i + 1 - (st > 0 ? st : 0));
        ushort4 ov;
        ov.x = f2b(s0 / cnt); ov.y = f2b(s1 / cnt);
        ov.z = f2b(s2 / cnt); ov.w = f2b(s3 / cnt);
        *(ushort4*)(Mp + (size_t)i * 1024) = ov;
        if (st >= 0) {
            const ushort4 hs = *(const ushort4*)(Hp + (size_t)st * 1024);
            s0 -= b2f(hs.x); s1 -= b2f(hs.y); s2 -= b2f(hs.z); s3 -= b2f(hs.w);
        }
    }
}

// ---------------------------------------------------------------------------
// ci[b,l,s] = dot(HM[b,l,0:512], SF[b,s,:]) — one thread per row, all 4 s.
// ---------------------------------------------------------------------------
__global__ __launch_bounds__(256)
void ci_kernel(const u16t* __restrict__ HM, const float* __restrict__ SF,
               float* __restrict__ CI)
{
    const int bl = blockIdx.x * 256 + threadIdx.x;   // 0..16383
    const int b = bl >> 11;
    const us8* h8 = (const us8*)(HM + (size_t)bl * 1024);
    const float4* f4 = (const float4*)(SF + (size_t)b * 4 * 512);
    float a0 = 0.f, a1 = 0.f, a2 = 0.f, a3 = 0.f;
    for (int k = 0; k < 64; ++k) {
        const us8 hv = h8[k];
        float hf[8];
#pragma unroll
        for (int j = 0; j < 8; ++j) hf[j] = b2f(hv[j]);
#pragma unroll
        for (int s = 0; s < 4; ++s) {
            const float4 x = f4[s * 128 + k * 2];
            const float4 y = f4[s * 128 + k * 2 + 1];
            const float d = hf[0] * x.x + hf[1] * x.y + hf[2] * x.z + hf[3] * x.w
                          + hf[4] * y.x + hf[5] * y.y + hf[6] * y.z + hf[7] * y.w;
            if (s == 0) a0 += d; else if (s == 1) a1 += d;
            else if (s == 2) a2 += d; else a3 += d;
        }
    }
    float4 outv = make_float4(a0, a1, a2, a3);
    *(float4*)(CI + (size_t)bl * 4) = outv;
}

// ---------------------------------------------------------------------------
// HM(ld1024,cols0-511) = LN(HM + Rb) * w + b ; all bf16, math in fp32.
// In-place on HM; Rb bf16 ld512. One wave per row.
// ---------------------------------------------------------------------------
__global__ __launch_bounds__(256)
void ln_add_b(u16t* __restrict__ HM, const u16t* __restrict__ Rb,
              const float* __restrict__ w, const float* __restrict__ b)
{
    const int lane = threadIdx.x & 63, wid = threadIdx.x >> 6;
    const size_t row = (size_t)blockIdx.x * 4 + wid;
    u16t* x = HM + row * 1024;
    const u16t* r = Rb + row * 512;
    const int c0 = lane * 8;
    float v[8];
    {
        const us8 x8 = *(const us8*)(x + c0);
        const us8 r8 = *(const us8*)(r + c0);
#pragma unroll
        for (int j = 0; j < 8; ++j) v[j] = b2f(x8[j]) + b2f(r8[j]);
    }
    float s = 0.f;
#pragma unroll
    for (int j = 0; j < 8; ++j) s += v[j];
#pragma unroll
    for (int off = 1; off < 64; off <<= 1) s += __shfl_xor(s, off);
    const float mean = s * (1.f / 512.f);
    float q = 0.f;
#pragma unroll
    for (int j = 0; j < 8; ++j) { const float dd = v[j] - mean; q += dd * dd; }
#pragma unroll
    for (int off = 1; off < 64; off <<= 1) q += __shfl_xor(q, off);
    const float rstd = rsqrtf(q * (1.f / 512.f) + 1e-5f);
    us8 o8;
#pragma unroll
    for (int j = 0; j < 8; ++j)
        o8[j] = f2b((v[j] - mean) * rstd * w[c0 + j] + b[c0 + j]);
    *(us8*)(x + c0) = o8;
}

// ---------------------------------------------------------------------------
// V transpose: Vt[b,h,d,l] (bf16) from QKVb[b,l,1024+h*128+d] (bf16).
// grid (L/64, B*H), block 256.
// ---------------------------------------------------------------------------
__global__ __launch_bounds__(256)
void vtprep(const u16t* __restrict__ QKVb, u16t* __restrict__ Vt)
{
    __shared__ u16t T[128 * 72];
    const int tid = threadIdx.x;
    const int l0 = blockIdx.x * 64;
    const int bh = blockIdx.y, b = bh >> 2, h = bh & 3;
#pragma unroll
    for (int it = 0; it < 4; ++it) {
        const int e = it * 256 + tid;
        const int l = e >> 4, dc = e & 15;
        const us8 v = *(const us8*)(QKVb + ((size_t)(b * 2048 + l0 + l)) * 1536
                                   + 1024 + h * 128 + dc * 8);
#pragma unroll
        for (int j = 0; j < 8; ++j) T[(dc * 8 + j) * 72 + l] = v[j];
    }
    __syncthreads();
#pragma unroll
    for (int it = 0; it < 4; ++it) {
        const int e = it * 256 + tid;
        const int d = e >> 3, lc = e & 7;
        const us8 ov = *(const us8*)&T[d * 72 + lc * 8];
        *(us8*)(Vt + ((size_t)bh * 128 + d) * 2048 + l0 + lc * 8) = ov;
    }
}

// ---------------------------------------------------------------------------
// MFMA flash attention, 2-phase pipelined (counted vmcnt), defer-max THR=8,
// grid (16, 32) = 512 blocks, 512 thr. XCD-grouped (b,h).  [round-7 proven]
// ---------------------------------------------------------------------------
__global__ __launch_bounds__(512)
void attn_bf16(const u16t* __restrict__ QKVb, const u16t* __restrict__ Vt,
               u16t* __restrict__ AOb)
{
    __shared__ u16t Kt[2][8192];
    __shared__ u16t Vtl[2][8192];
    __shared__ u16t Pl[8192];
    const int tid = threadIdx.x, lane = tid & 63, w = tid >> 6;
    const int l15 = lane & 15, l4 = lane >> 4;
    const unsigned bid = blockIdx.y * gridDim.x + blockIdx.x;  // 0..511
    const int xcd = bid & 7, idx = bid >> 3;
    const int bh = xcd * 4 + (idx & 3);
    const int q0 = (idx >> 2) * 128;
    const int b = bh >> 2, h = bh & 3;
    const float SCALE = 0.08838834764831845f;   // 1/sqrt(128)

    int krow[2], kdoff[2], vd[2], vkoff[2], se0[2];
#pragma unroll
    for (int it = 0; it < 2; ++it) {
        const int e = it * 512 + tid;
        se0[it] = it * 512 + (tid & 448);
        const int dblk = e >> 6, key = e & 63;
        krow[it] = key ^ (dblk & 3);
        kdoff[it] = dblk * 8;
        const int kb = e >> 7, d = e & 127;
        vd[it] = d ^ (kb & 3);
        vkoff[it] = kb * 8;
    }
    auto STAGE = [&](int buf, int k0) {
#pragma unroll
        for (int it = 0; it < 2; ++it)
            gload16(QKVb + ((size_t)(b * 2048 + k0 + krow[it])) * 1536 + 512 + h * 128 + kdoff[it],
                    &Kt[buf][(size_t)se0[it] * 8]);
#pragma unroll
        for (int it = 0; it < 2; ++it)
            gload16(Vt + ((size_t)bh * 128 + vd[it]) * 2048 + k0 + vkoff[it],
                    &Vtl[buf][(size_t)se0[it] * 8]);
    };

    s16x8 qf[4];
    {
        const u16t* qp = QKVb + ((size_t)(b * 2048 + q0 + w * 16 + l15)) * 1536
                         + h * 128 + l4 * 8;
#pragma unroll
        for (int ks = 0; ks < 4; ++ks) qf[ks] = *(const s16x8*)(qp + ks * 32);
    }
    asm volatile("s_waitcnt vmcnt(0)" ::: "memory");

    f32x4 o[8];
#pragma unroll
    for (int i = 0; i < 8; ++i) o[i] = (f32x4){0.f, 0.f, 0.f, 0.f};
    f32x4 m_run, lsum;
#pragma unroll
    for (int r = 0; r < 4; ++r) { m_run[r] = -1e30f; lsum[r] = 0.f; }

    const int ls = l15 ^ l4;
    STAGE(0, 0);
    for (int kt = 0; kt < 32; ++kt) {
        const int cur = kt & 1;
        if (kt + 1 < 32) {
            STAGE(cur ^ 1, (kt + 1) * 64);
            asm volatile("s_waitcnt vmcnt(4)" ::: "memory");
        } else {
            asm volatile("s_waitcnt vmcnt(0)" ::: "memory");
        }
        __builtin_amdgcn_s_barrier();

        f32x4 s[4];
#pragma unroll
        for (int ni = 0; ni < 4; ++ni) s[ni] = (f32x4){0.f, 0.f, 0.f, 0.f};
#pragma unroll
        for (int ks = 0; ks < 4; ++ks) {
#pragma unroll
            for (int ni = 0; ni < 4; ++ni) {
                const s16x8 kf = *(const s16x8*)&Kt[cur][(size_t)((ks * 4 + l4) * 64 + ni * 16 + ls) * 8];
                s[ni] = __builtin_amdgcn_mfma_f32_16x16x32_bf16(qf[ks], kf, s[ni], 0, 0, 0);
            }
        }
        f32x4 mx;
#pragma unroll
        for (int r = 0; r < 4; ++r)
            mx[r] = fmaxf(fmaxf(s[0][r], s[1][r]), fmaxf(s[2][r], s[3][r])) * SCALE;
#pragma unroll
        for (int off = 1; off < 16; off <<= 1)
#pragma unroll
            for (int r = 0; r < 4; ++r) mx[r] = fmaxf(mx[r], __shfl_xor(mx[r], off));
        bool small = true;
#pragma unroll
        for (int r = 0; r < 4; ++r) small = small && (mx[r] <= m_run[r] + 8.f);
        if (!__all(small)) {
            f32x4 corr;
#pragma unroll
            for (int r = 0; r < 4; ++r) {
                const float nm = fmaxf(m_run[r], mx[r]);
                corr[r] = __expf(m_run[r] - nm);
                m_run[r] = nm;
                lsum[r] *= corr[r];
            }
#pragma unroll
            for (int ni = 0; ni < 8; ++ni)
#pragma unroll
                for (int r = 0; r < 4; ++r) o[ni][r] *= corr[r];
        }
        float p[4][4];
#pragma unroll
        for (int ni = 0; ni < 4; ++ni)
#pragma unroll
            for (int r = 0; r < 4; ++r) {
                p[ni][r] = __expf(s[ni][r] * SCALE - m_run[r]);
                lsum[r] += p[ni][r];
            }
#pragma unroll
        for (int ni = 0; ni < 4; ++ni) {
            const int key = ni * 16 + l15;
            const int kb = key >> 3, kj = key & 7;
#pragma unroll
            for (int r = 0; r < 4; ++r)
                Pl[(size_t)((w * 8 + kb) * 16 + l4 * 4 + r) * 8 + kj] = f2b(p[ni][r]);
        }
#pragma unroll
        for (int kk = 0; kk < 2; ++kk) {
            const s16x8 pa = *(const s16x8*)&Pl[(size_t)((w * 8 + kk * 4 + l4) * 16 + l15) * 8];
#pragma unroll
            for (int ni = 0; ni < 8; ++ni) {
                const s16x8 vf = *(const s16x8*)&Vtl[cur][(size_t)((kk * 4 + l4) * 128 + ni * 16 + ls) * 8];
                o[ni] = __builtin_amdgcn_mfma_f32_16x16x32_bf16(pa, vf, o[ni], 0, 0, 0);
            }
        }
        __builtin_amdgcn_s_barrier();
    }
#pragma unroll
    for (int off = 1; off < 16; off <<= 1)
#pragma unroll
        for (int r = 0; r < 4; ++r) lsum[r] += __shfl_xor(lsum[r], off);
    f32x4 inv;
#pragma unroll
    for (int r = 0; r < 4; ++r) inv[r] = 1.f / lsum[r];
#pragma unroll
    for (int ni = 0; ni < 8; ++ni)
#pragma unroll
        for (int r = 0; r < 4; ++r)
            AOb[((size_t)(b * 2048 + q0 + w * 16 + l4 * 4 + r)) * 512
                + h * 128 + ni * 16 + l15] = f2b(o[ni][r] * inv[r]);
}

// ---------------------------------------------------------------------------
// concat -> padded bf16 [M,576], vectorized (4-col groups; 576 = 144*4).
// ---------------------------------------------------------------------------
__global__ __launch_bounds__(256)
void concat_b(const float* __restrict__ CI, const u16t* __restrict__ HM,
              u16t* __restrict__ OUTC)
{
    const size_t total = (size_t)16384 * 144;
    const size_t i = (size_t)blockIdx.x * 256 + threadIdx.x;
    if (i >= total) return;
    const int gcol = (int)(i % 144);
    const size_t row = i / 144;
    ushort4 v;
    if (gcol == 0) {
        const float4 c = *(const float4*)(CI + row * 4);
        v.x = f2b(c.x); v.y = f2b(c.y); v.z = f2b(c.z); v.w = f2b(c.w);
    } else if (gcol < 129) {
        v = *(const ushort4*)(HM + row * 1024 + (size_t)(gcol - 1) * 4);
    } else {
        v.x = 0; v.y = 0; v.z = 0; v.w = 0;
    }
    *(ushort4*)(OUTC + row * 576 + (size_t)gcol * 4) = v;
}

// ---------------------------------------------------------------------------
// converters
// ---------------------------------------------------------------------------
struct CvtJob { const float* s; u16t* d; unsigned n8; unsigned blk0; };
struct CvtJobs { CvtJob j[8]; };

__global__ __launch_bounds__(256)
void cvt_batch(CvtJobs jobs)
{
    int lo = 0;
#pragma unroll
    for (int i = 1; i < 8; ++i) if (blockIdx.x >= jobs.j[i].blk0) lo = i;
    const float* src = jobs.j[lo].s;
    u16t* dst = jobs.j[lo].d;
    const size_t i = (size_t)(blockIdx.x - jobs.j[lo].blk0) * 256 + threadIdx.x;
    if (i >= jobs.j[lo].n8) return;
    const float4 a = ((const float4*)src)[i * 2];
    const float4 b = ((const float4*)src)[i * 2 + 1];
    us8 o;
    o[0] = f2b(a.x); o[1] = f2b(a.y); o[2] = f2b(a.z); o[3] = f2b(a.w);
    o[4] = f2b(b.x); o[5] = f2b(b.y); o[6] = f2b(b.z); o[7] = f2b(b.w);
    ((us8*)dst)[i] = o;
}

// generic pad (scalar) — only for sc not divisible by 8 (adapter 516->576)
__global__ __launch_bounds__(256)
void cvt_pad(const float* __restrict__ src, u16t* __restrict__ dst,
             int rows, int sc, int dc)
{
    const size_t i = (size_t)blockIdx.x * 256 + threadIdx.x;
    const size_t total = (size_t)rows * dc;
    if (i >= total) return;
    const int c = (int)(i % dc);
    const size_t r = i / dc;
    dst[i] = (c < sc) ? f2b(src[r * sc + c]) : (u16t)0;
}

// vectorized pad for 8-aligned sc/dc (x: 80->128, enc0_w, cls_w1)
__global__ __launch_bounds__(256)
void cvt_pad8(const float* __restrict__ src, u16t* __restrict__ dst,
              int rows, int sc, int dc)
{
    const int gpr = dc >> 3;
    const size_t total = (size_t)rows * gpr;
    const size_t i = (size_t)blockIdx.x * 256 + threadIdx.x;
    if (i >= total) return;
    const int g = (int)(i % gpr);
    const size_t r = i / gpr;
    us8 o;
    if (g * 8 < sc) {
        const float* p = src + r * sc + g * 8;
        const float4 a = *(const float4*)p;
        const float4 b = *(const float4*)(p + 4);
        o[0] = f2b(a.x); o[1] = f2b(a.y); o[2] = f2b(a.z); o[3] = f2b(a.w);
        o[4] = f2b(b.x); o[5] = f2b(b.y); o[6] = f2b(b.z); o[7] = f2b(b.w);
    } else {
        o[0] = 0; o[1] = 0; o[2] = 0; o[3] = 0;
        o[4] = 0; o[5] = 0; o[6] = 0; o[7] = 0;
    }
    *(us8*)(dst + r * dc + g * 8) = o;
}

// fuse [layers,512,512] lw,mw -> [layers,512,1024], vectorized 8 elems/thread
__global__ __launch_bounds__(256)
void cvt_fuse(const float* __restrict__ lsrc, const float* __restrict__ msrc,
              u16t* __restrict__ dst, int n8)
{
    const int idx = blockIdx.x * 256 + threadIdx.x;
    if (idx >= n8) return;
    const int k8 = idx & 63;              // 64 groups of 8 per 512-col row
    const int nn = (idx >> 6) & 511;
    const int i = idx >> 15;
    const size_t sbase = (size_t)i * 262144 + (size_t)nn * 512 + (size_t)k8 * 8;
    const size_t dbase = (size_t)i * 524288 + (size_t)nn * 1024 + (size_t)k8 * 8;
    {
        const float4 a = *(const float4*)(lsrc + sbase);
        const float4 b = *(const float4*)(lsrc + sbase + 4);
        us8 o;
        o[0] = f2b(a.x); o[1] = f2b(a.y); o[2] = f2b(a.z); o[3] = f2b(a.w);
        o[4] = f2b(b.x); o[5] = f2b(b.y); o[6] = f2b(b.z); o[7] = f2b(b.w);
        *(us8*)(dst + dbase) = o;
    }
    {
        const float4 a = *(const float4*)(msrc + sbase);
        const float4 b = *(const float4*)(msrc + sbase + 4);
        us8 o;
        o[0] = f2b(a.x); o[1] = f2b(a.y); o[2] = f2b(a.z); o[3] = f2b(a.w);
        o[4] = f2b(b.x); o[5] = f2b(b.y); o[6] = f2b(b.z); o[7] = f2b(b.w);
        *(us8*)(dst + dbase + 512) = o;
    }
}

__global__ __launch_bounds__(256)
void bias_fuse(const float* __restrict__ a, const float* __restrict__ b,
               float* __restrict__ dst, int n)
{
    const int i = blockIdx.x * 256 + threadIdx.x;
    if (i < n) dst[i] = a[i] + b[i];
}

// ---------------------------------------------------------------------------
// final tiny GEMM: out[M,16] = T1b[M,512](bf16) @ W2[16,512]^T + b2   (fp32)
// ---------------------------------------------------------------------------
__global__ __launch_bounds__(256)
void cls2_kernel(const u16t* __restrict__ T1b, const float* __restrict__ W2,
                 const float* __restrict__ b2, float* __restrict__ out)
{
    const int t = threadIdx.x;
    const int r = blockIdx.x * 16 + (t >> 4), c = t & 15;
    const us8* a = (const us8*)(T1b + (size_t)r * 512);
    const float4* wv = (const float4*)(W2 + (size_t)c * 512);
    float acc = 0.f;
    for (int k = 0; k < 64; ++k) {
        const us8 hv = a[k];
        const float4 x = wv[k * 2], y = wv[k * 2 + 1];
        acc += b2f(hv[0]) * x.x + b2f(hv[1]) * x.y + b2f(hv[2]) * x.z + b2f(hv[3]) * x.w
             + b2f(hv[4]) * y.x + b2f(hv[5]) * y.y + b2f(hv[6]) * y.z + b2f(hv[7]) * y.w;
    }
    out[(size_t)r * 16 + c] = acc + b2[c];
}

// ---------------------------------------------------------------------------
extern "C" void kernel_launch(void* const* d_in, const int* in_sizes, int n_in,
                              void* d_out, int out_size, void* d_ws, size_t ws_size,
                              hipStream_t stream)
{
    (void)in_sizes; (void)n_in; (void)out_size; (void)ws_size;
    const int M = 16384;   // B*L

    const float* x        = (const float*)d_in[0];
    const float* spk_emb  = (const float*)d_in[1];
    const float* enc0_w   = (const float*)d_in[2];
    const float* enc0_b   = (const float*)d_in[3];
    const float* enc_lw   = (const float*)d_in[4];
    const float* enc_lb   = (const float*)d_in[5];
    const float* enc_mw   = (const float*)d_in[6];
    const float* enc_mb   = (const float*)d_in[7];
    const float* spk_w1   = (const float*)d_in[8];
    const float* spk_b1   = (const float*)d_in[9];
    const float* spk_w2   = (const float*)d_in[10];
    const float* spk_b2   = (const float*)d_in[11];
    const float* spk_w3   = (const float*)d_in[12];
    const float* spk_b3   = (const float*)d_in[13];
    const float* tr_in_w  = (const float*)d_in[14];
    const float* tr_in_b  = (const float*)d_in[15];
    const float* tr_out_w = (const float*)d_in[16];
    const float* tr_out_b = (const float*)d_in[17];
    const float* tr_ln1_w = (const float*)d_in[18];
    const float* tr_ln1_b = (const float*)d_in[19];
    const float* tr_ff1_w = (const float*)d_in[20];
    const float* tr_ff1_b = (const float*)d_in[21];
    const float* tr_ff2_w = (const float*)d_in[22];
    const float* tr_ff2_b = (const float*)d_in[23];
    const float* tr_ln2_w = (const float*)d_in[24];
    const float* tr_ln2_b = (const float*)d_in[25];
    const float* adpt_w   = (const float*)d_in[26];
    const float* adpt_b   = (const float*)d_in[27];
    const float* post_lw  = (const float*)d_in[28];
    const float* post_lb  = (const float*)d_in[29];
    const float* post_mw  = (const float*)d_in[30];
    const float* post_mb  = (const float*)d_in[31];
    const float* cls_w1   = (const float*)d_in[32];
    const float* cls_b1   = (const float*)d_in[33];
    const float* cls_w2   = (const float*)d_in[34];
    const float* cls_b2   = (const float*)d_in[35];

    // ---- workspace layout ----
    char* wsp = (char*)d_ws;
    size_t off = 0;
    auto alloc = [&](size_t bytes) -> void* {
        void* p = wsp + off; off += (bytes + 255) & ~(size_t)255; return p;
    };
    u16t*  T1b  = (u16t*) alloc((size_t)M * 512 * 2);      // bf16 LN-residual / cls1 out
    u16t*  HM0  = (u16t*) alloc((size_t)M * 1024 * 2);     // [h | means] ping
    u16t*  AOb  = (u16t*) alloc((size_t)M * 512 * 2);      // attn out
    u16t*  BIG  = (u16t*) alloc((size_t)M * 2048 * 2);     // HM1 | xb | QKV+Vt | F | Xcat
    float* CI   = (float*)alloc((size_t)M * 4 * 4);
    float* S3   = (float*)alloc(32 * 512 * 4);
    u16t* enc0_wb   = (u16t*)alloc(512 * 128 * 2);
    u16t* encFW     = (u16t*)alloc((size_t)8 * 512 * 1024 * 2);
    float* encFB    = (float*)alloc(8 * 512 * 4);
    u16t* spk_embb  = (u16t*)alloc(32 * 192 * 2);
    u16t* spk_w1b   = (u16t*)alloc(512 * 192 * 2);
    u16t* spk_w2b   = (u16t*)alloc(512 * 512 * 2);
    u16t* spk_w3b   = (u16t*)alloc(512 * 512 * 2);
    u16t* tr_in_wb  = (u16t*)alloc((size_t)4 * 1536 * 512 * 2);
    u16t* tr_out_wb = (u16t*)alloc((size_t)4 * 512 * 512 * 2);
    u16t* tr_ff1_wb = (u16t*)alloc((size_t)4 * 2048 * 512 * 2);
    u16t* tr_ff2_wb = (u16t*)alloc((size_t)4 * 2048 * 512 * 2);
    u16t* adpt_wb   = (u16t*)alloc(512 * 576 * 2);
    u16t* postFW    = (u16t*)alloc((size_t)6 * 512 * 1024 * 2);
    float* postFB   = (float*)alloc(6 * 512 * 4);
    u16t* cls_w1b   = (u16t*)alloc(512 * 512 * 2);
    u16t* S1b       = (u16t*)alloc(32 * 512 * 2);
    u16t* S2b       = (u16t*)alloc(32 * 512 * 2);

    u16t* HM1   = BIG;                       // [M,1024] during FSMN phases
    u16t* xb    = BIG;                       // [M,128] before enc0 only
    u16t* QKVb  = BIG;                       // [M,1536] during transformer
    u16t* Vt    = BIG + (size_t)M * 1536;    // [B*H,128,2048]
    u16t* Fb    = BIG;                       // [M,2048] FFN hidden
    u16t* Xcatb = BIG;                       // [M,576] concat
    u16t* HMs[2] = {HM0, HM1};

    // 13 params: A,lda, W,ldw, bias, C,ldc, Cb,ldcb, m,n,k, flags
    auto gemm = [&](const u16t* A, int lda, const u16t* W, int ldw,
                    const float* bias, float* C, int ldc, u16t* Cb, int ldcb,
                    int m, int n, int k, int flags) {
        dim3 g(n / 128, (m + 127) / 128);
        gemm_bf16<<<g, dim3(512), 0, stream>>>(A, lda, W, ldw, bias,
                                               C, ldc, Cb, ldcb, m, n, k, flags);
    };

    // --- weight & input conversion ---
    cvt_pad8<<<dim3((unsigned)(((size_t)M * 16 + 255) / 256)), dim3(256), 0, stream>>>(
        x, xb, M, 80, 128);
    cvt_pad8<<<dim3((512 * 16 + 255) / 256), dim3(256), 0, stream>>>(
        enc0_w, enc0_wb, 512, 80, 128);
    cvt_fuse<<<dim3(262144 / 256), dim3(256), 0, stream>>>(enc_lw, enc_mw, encFW, 262144);
    bias_fuse<<<dim3(16), dim3(256), 0, stream>>>(enc_lb, enc_mb, encFB, 4096);
    {
        // batched fp32->bf16 conversions (8 jobs, one launch)
        CvtJobs jobs;
        const float* srcs[8] = {spk_emb, spk_w1, spk_w2, spk_w3,
                                tr_in_w, tr_out_w, tr_ff1_w, tr_ff2_w};
        u16t* dsts[8] = {spk_embb, spk_w1b, spk_w2b, spk_w3b,
                         tr_in_wb, tr_out_wb, tr_ff1_wb, tr_ff2_wb};
        const size_t ns[8] = {32 * 192, (size_t)512 * 192, (size_t)512 * 512, (size_t)512 * 512,
                              (size_t)4 * 1536 * 512, (size_t)4 * 512 * 512,
                              (size_t)4 * 2048 * 512, (size_t)4 * 2048 * 512};
        unsigned blk = 0;
        for (int i = 0; i < 8; ++i) {
            jobs.j[i].s = srcs[i];
            jobs.j[i].d = dsts[i];
            jobs.j[i].n8 = (unsigned)(ns[i] / 8);
            jobs.j[i].blk0 = blk;
            blk += (jobs.j[i].n8 + 255) / 256;
        }
        cvt_batch<<<dim3(blk), dim3(256), 0, stream>>>(jobs);
    }
    cvt_pad<<<dim3((unsigned)(((size_t)512 * 576 + 255) / 256)), dim3(256), 0, stream>>>(
        adpt_w, adpt_wb, 512, 516, 576);
    cvt_fuse<<<dim3(196608 / 256), dim3(256), 0, stream>>>(post_lw, post_mw, postFW, 196608);
    bias_fuse<<<dim3(12), dim3(256), 0, stream>>>(post_lb, post_mb, postFB, 3072);
    cvt_pad8<<<dim3((512 * 64 + 255) / 256), dim3(256), 0, stream>>>(
        cls_w1, cls_w1b, 512, 512, 512);

    // --- encoder: enc0 writes h into HM0 cols 0-511 ---
    gemm(xb, 128, enc0_wb, 128, enc0_b,
         nullptr, 0, HM0, 1024, M, 512, 128, GB_WB16);
    for (int i = 0; i < 8; ++i) {   // strides 1..128; fused lin+mem GEMM
        u16t* src = HMs[i & 1];
        u16t* dst = HMs[(i + 1) & 1];
        fsmn_means_b<<<dim3(128), dim3(256), 0, stream>>>(src, 1 << i);
        gemm(src, 1024, encFW + (size_t)i * 524288, 1024, encFB + (size_t)i * 512,
             nullptr, 0, dst, 1024, M, 512, 1024, GB_WB16);
    }
    // h_enc now in HM0 (bf16 residual stream)

    // --- speaker MLP ---
    gemm(spk_embb, 192, spk_w1b, 192, spk_b1,
         nullptr, 0, S1b, 512, 32, 512, 192, GB_RELU | GB_WB16);
    gemm(S1b, 512, spk_w2b, 512, spk_b2,
         nullptr, 0, S2b, 512, 32, 512, 512, GB_RELU | GB_WB16);
    gemm(S2b, 512, spk_w3b, 512, spk_b3,
         S3, 512, nullptr, 0, 32, 512, 512, GB_WF32);

    // --- context-independent scores ---
    ci_kernel<<<dim3(64), dim3(256), 0, stream>>>(HM0, S3, CI);

    // --- transformer (bf16 residual lives in HM0 cols 0-511) ---
    for (int i = 0; i < 4; ++i) {
        gemm(HM0, 1024, tr_in_wb + (size_t)i * 786432, 512, tr_in_b + (size_t)i * 1536,
             nullptr, 0, QKVb, 1536, M, 1536, 512, GB_WB16);
        vtprep<<<dim3(32, 32), dim3(256), 0, stream>>>(QKVb, Vt);
        attn_bf16<<<dim3(16, 32), dim3(512), 0, stream>>>(QKVb, Vt, AOb);
        gemm(AOb, 512, tr_out_wb + (size_t)i * 262144, 512, tr_out_b + (size_t)i * 512,
             nullptr, 0, T1b, 512, M, 512, 512, GB_WB16);
        ln_add_b<<<dim3(M / 4), dim3(256), 0, stream>>>(
            HM0, T1b, tr_ln1_w + (size_t)i * 512, tr_ln1_b + (size_t)i * 512);
        gemm(HM0, 1024, tr_ff1_wb + (size_t)i * 1048576, 512, tr_ff1_b + (size_t)i * 2048,
             nullptr, 0, Fb, 2048, M, 2048, 512, GB_RELU | GB_WB16);
        gemm(Fb, 2048, tr_ff2_wb + (size_t)i * 1048576, 2048, tr_ff2_b + (size_t)i * 512,
             nullptr, 0, T1b, 512, M, 512, 2048, GB_WB16);
        ln_add_b<<<dim3(M / 4), dim3(256), 0, stream>>>(
            HM0, T1b, tr_ln2_w + (size_t)i * 512, tr_ln2_b + (size_t)i * 512);
    }

    // --- concat + adapter ---
    concat_b<<<dim3((unsigned)(((size_t)M * 144 + 255) / 256)), dim3(256), 0, stream>>>(CI, HM0, Xcatb);
    gemm(Xcatb, 576, adpt_wb, 576, adpt_b,
         nullptr, 0, HM0, 1024, M, 512, 576, GB_WB16);

    // --- post FSMN (6 fused layers, strides 1..32) ---
    for (int i = 0; i < 6; ++i) {
        u16t* src = HMs[i & 1];
        u16t* dst = HMs[(i + 1) & 1];
        fsmn_means_b<<<dim3(128), dim3(256), 0, stream>>>(src, 1 << i);
        gemm(src, 1024, postFW + (size_t)i * 524288, 1024, postFB + (size_t)i * 512,
             nullptr, 0, dst, 1024, M, 512, 1024, GB_WB16);
    }
    // result in HM0

    // --- classifier ---
    gemm(HM0, 1024, cls_w1b, 512, cls_b1,
         nullptr, 0, T1b, 512, M, 512, 512, GB_RELU | GB_WB16);
    cls2_kernel<<<dim3(M / 16), dim3(256), 0, stream>>>(T1b, cls_w2, cls_b2, (float*)d_out);
}